// Round 1
// baseline (2156.150 us; speedup 1.0000x reference)
//
#include <hip/hip_runtime.h>
#include <hip/hip_bf16.h>

#define NNODES 131072
#define NEDGES 2097152
#define NB     128
#define NPG    1024   // nodes per graph
#define EPG    16384  // edges per graph

// ws layout in floats
#define OFF_DEG    0                          // 2*NNODES
#define OFF_POOLED (2*NNODES)                 // 2*NB*64 = 16384
#define OFF_WT     (OFF_POOLED + 2*NB*64)     // 6*4096
#define OFF_H      (OFF_WT + 6*4096)          // 2*NNODES*64

// ---------------- transpose the six 64x64 node-MLP weights: wt[m][f][k] = W_m[k][f]
__global__ void wt_transpose(const float* __restrict__ w0, const float* __restrict__ w1,
                             const float* __restrict__ w2, const float* __restrict__ w3,
                             const float* __restrict__ w4, const float* __restrict__ w5,
                             float* __restrict__ wt) {
    int m = blockIdx.x;
    const float* w = (m == 0) ? w0 : (m == 1) ? w1 : (m == 2) ? w2
                   : (m == 3) ? w3 : (m == 4) ? w4 : w5;
    for (int idx = threadIdx.x; idx < 4096; idx += blockDim.x) {
        int f = idx >> 6, k = idx & 63;
        wt[m * 4096 + idx] = w[k * 64 + f];
    }
}

// ---------------- deg[n] = segment_sum(ew, dst)   (both branches; +1 applied later)
__global__ __launch_bounds__(256) void deg_kernel(const int* __restrict__ eia, const float* __restrict__ eaa,
                                                  const int* __restrict__ eib, const float* __restrict__ eab,
                                                  float* __restrict__ deg) {
    int i = blockIdx.x * 256 + threadIdx.x;          // 0 .. 2*NEDGES-1
    int br = (i >= NEDGES) ? 1 : 0;
    int e  = i - br * NEDGES;
    const int*   ei = br ? eib : eia;
    const float* ea = br ? eab : eaa;
    int dst = ei[NEDGES + e];
    unsafeAtomicAdd(&deg[br * NNODES + dst], ea[e]);
}

// ---------------- fused 3-layer node MLP: h = relu(relu(x@W1+b1)@W2+b2)@Wg
// lane = node; x row in 64 VGPRs; weights via wave-uniform (scalar) loads of
// transposed matrices; padded LDS bounce converts runtime-f writes into
// statically-indexed register reads for the next layer.
__global__ __launch_bounds__(128) void node_mlp(
    const float* __restrict__ xa, const float* __restrict__ xb,
    const float* __restrict__ wt,
    const float* __restrict__ b1a, const float* __restrict__ b2a,
    const float* __restrict__ b1b, const float* __restrict__ b2b,
    float* __restrict__ hout) {
    __shared__ float bounce[128 * 65];
    const int br = blockIdx.y;
    const float* x   = br ? xb : xa;
    const float* wt1 = wt + br * 3 * 4096;
    const float* wt2 = wt1 + 4096;
    const float* wt3 = wt2 + 4096;
    const float* b1  = br ? b1b : b1a;
    const float* b2  = br ? b2b : b2a;
    const int node = blockIdx.x * 128 + threadIdx.x;

    float xr[64];
    const float4* xp = reinterpret_cast<const float4*>(x + (size_t)node * 64);
#pragma unroll
    for (int i = 0; i < 16; ++i) {
        float4 v = xp[i];
        xr[4 * i + 0] = v.x; xr[4 * i + 1] = v.y; xr[4 * i + 2] = v.z; xr[4 * i + 3] = v.w;
    }
    float* myrow = &bounce[threadIdx.x * 65];

    // layer 1
    for (int f = 0; f < 64; ++f) {
        const float* w = wt1 + f * 64;
        float acc = b1[f];
#pragma unroll
        for (int k = 0; k < 64; ++k) acc = fmaf(xr[k], w[k], acc);
        myrow[f] = fmaxf(acc, 0.f);
    }
#pragma unroll
    for (int k = 0; k < 64; ++k) xr[k] = myrow[k];

    // layer 2
    for (int f = 0; f < 64; ++f) {
        const float* w = wt2 + f * 64;
        float acc = b2[f];
#pragma unroll
        for (int k = 0; k < 64; ++k) acc = fmaf(xr[k], w[k], acc);
        myrow[f] = fmaxf(acc, 0.f);
    }
#pragma unroll
    for (int k = 0; k < 64; ++k) xr[k] = myrow[k];

    // layer 3 (no bias, no relu) -> global
    float* hp = hout + (size_t)br * NNODES * 64 + (size_t)node * 64;
    for (int f = 0; f < 64; ++f) {
        const float* w = wt3 + f * 64;
        float acc = 0.f;
#pragma unroll
        for (int k = 0; k < 64; ++k) acc = fmaf(xr[k], w[k], acc);
        hp[f] = acc;
    }
}

// ---------------- fused GCN aggregation + self loop + bias + relu + graph-sum pool
// block = (graph g, feature-quarter q, branch br); LDS accumulator 1024x16 f32.
__global__ __launch_bounds__(256) void gcn_pool(
    const int* __restrict__ eia, const float* __restrict__ eaa,
    const int* __restrict__ eib, const float* __restrict__ eab,
    const float* __restrict__ deg, const float* __restrict__ h,
    const float* __restrict__ bga, const float* __restrict__ bgb,
    float* __restrict__ pooled) {
    __shared__ float acc[NPG * 16];   // 64 KB
    const int g  = blockIdx.x;
    const int q  = blockIdx.y;
    const int br = blockIdx.z;
    const int*   ei = br ? eib : eia;
    const float* ea = br ? eab : eaa;
    const float* dg = deg + br * NNODES;
    const float* hh = h + (size_t)br * NNODES * 64;
    const float* bg = br ? bgb : bga;
    const int tid = threadIdx.x;

    for (int i = tid; i < NPG * 16; i += 256) acc[i] = 0.f;
    __syncthreads();

    const int f16   = tid & 15;
    const int es    = tid >> 4;        // 16 edges per iteration
    const int fof   = q * 16 + f16;
    const int gnode = g * NPG;
    const int ebase = g * EPG;

#pragma unroll 2
    for (int it = 0; it < EPG / 16; ++it) {
        int e   = ebase + it * 16 + es;
        int src = ei[e];
        int dst = ei[NEDGES + e];
        float w = ea[e];
        float nrm = rsqrtf(dg[src] + 1.f) * w * rsqrtf(dg[dst] + 1.f);
        float hv  = hh[(size_t)src * 64 + fof];
        unsafeAtomicAdd(&acc[(dst - gnode) * 16 + f16], nrm * hv);
    }
    __syncthreads();

    // self-loop + bias + relu + partial graph sum
    float psum = 0.f;
    float bias = bg[fof];
    for (int n = es; n < NPG; n += 16) {
        float d = dg[gnode + n] + 1.f;
        float v = acc[n * 16 + f16] + hh[(size_t)(gnode + n) * 64 + fof] * (1.f / d) + bias;
        psum += fmaxf(v, 0.f);
    }
    __syncthreads();
    acc[tid] = psum;
    __syncthreads();
    if (tid < 16) {
        float s = 0.f;
#pragma unroll
        for (int j = 0; j < 16; ++j) s += acc[j * 16 + tid];
        pooled[br * (NB * 64) + g * 64 + q * 16 + tid] = s;
    }
}

// ---------------- final MLP heads: [gsp||gap] x2 branches + linker -> lin1 -> lin2 -> 5 heads
__global__ __launch_bounds__(128) void final_mlp(
    const float* __restrict__ pooled, const float* __restrict__ linker,
    const float* __restrict__ W1, const float* __restrict__ b1,
    const float* __restrict__ W2, const float* __restrict__ b2,
    const float* __restrict__ W3, const float* __restrict__ b3,
    const float* __restrict__ Wcb, const float* __restrict__ bcb,
    const float* __restrict__ Wom, const float* __restrict__ bom,
    const float* __restrict__ Wth, const float* __restrict__ bth,
    const float* __restrict__ Wph, const float* __restrict__ bph,
    float* __restrict__ out) {
    __shared__ float inv[260];
    __shared__ float x1[128];
    __shared__ float x2[64];
    const int g = blockIdx.x;
    const int t = threadIdx.x;
    if (t < 64) {
        float pa = pooled[g * 64 + t];
        float pb = pooled[NB * 64 + g * 64 + t];
        inv[t]       = pa;
        inv[64 + t]  = pa * (1.f / 1024.f);
        inv[128 + t] = pb;
        inv[192 + t] = pb * (1.f / 1024.f);
    }
    if (t == 0) inv[256] = linker[g];
    __syncthreads();

    {   // lin1: 257 -> 128
        float a = b1[t];
        for (int i = 0; i < 257; ++i) a = fmaf(inv[i], W1[i * 128 + t], a);
        x1[t] = fmaxf(a, 0.f);
    }
    __syncthreads();
    if (t < 64) {   // lin2: 128 -> 64
        float a = b2[t];
        for (int i = 0; i < 128; ++i) a = fmaf(x1[i], W2[i * 64 + t], a);
        x2[t] = fmaxf(a, 0.f);
    }
    __syncthreads();
    if (t < 8) {    // heads
        if (t == 0) {
            float a = b3[0];
            for (int i = 0; i < 64; ++i) a = fmaf(x2[i], W3[i], a);
            out[g] = a;
        } else if (t == 1) {
            float a = bcb[0];
            for (int i = 0; i < 64; ++i) a = fmaf(x2[i], Wcb[i], a);
            out[128 + g] = a;
        } else if (t < 4) {
            int j = t - 2; float a = bom[j];
            for (int i = 0; i < 64; ++i) a = fmaf(x2[i], Wom[i * 2 + j], a);
            out[256 + g * 2 + j] = a;
        } else if (t < 6) {
            int j = t - 4; float a = bth[j];
            for (int i = 0; i < 64; ++i) a = fmaf(x2[i], Wth[i * 2 + j], a);
            out[512 + g * 2 + j] = a;
        } else {
            int j = t - 6; float a = bph[j];
            for (int i = 0; i < 64; ++i) a = fmaf(x2[i], Wph[i * 2 + j], a);
            out[768 + g * 2 + j] = a;
        }
    }
}

extern "C" void kernel_launch(void* const* d_in, const int* in_sizes, int n_in,
                              void* d_out, int out_size, void* d_ws, size_t ws_size,
                              hipStream_t stream) {
    const float* x_a  = (const float*)d_in[0];
    const int*   ei_a = (const int*)d_in[1];
    const float* ea_a = (const float*)d_in[2];
    const float* x_b  = (const float*)d_in[4];
    const int*   ei_b = (const int*)d_in[5];
    const float* ea_b = (const float*)d_in[6];
    const float* linker = (const float*)d_in[8];
    const float* W_pre1_a = (const float*)d_in[9];
    const float* b_pre1_a = (const float*)d_in[10];
    const float* W_pre2_a = (const float*)d_in[11];
    const float* b_pre2_a = (const float*)d_in[12];
    const float* W_gcn_a  = (const float*)d_in[13];
    const float* b_gcn_a  = (const float*)d_in[14];
    const float* W_pre1_b = (const float*)d_in[15];
    const float* b_pre1_b = (const float*)d_in[16];
    const float* W_pre2_b = (const float*)d_in[17];
    const float* b_pre2_b = (const float*)d_in[18];
    const float* W_gcn_b  = (const float*)d_in[19];
    const float* b_gcn_b  = (const float*)d_in[20];
    const float* W_lin1 = (const float*)d_in[21];
    const float* b_lin1 = (const float*)d_in[22];
    const float* W_lin2 = (const float*)d_in[23];
    const float* b_lin2 = (const float*)d_in[24];
    const float* W_lin3 = (const float*)d_in[25];
    const float* b_lin3 = (const float*)d_in[26];
    const float* W_cb = (const float*)d_in[27];
    const float* b_cb = (const float*)d_in[28];
    const float* W_om = (const float*)d_in[29];
    const float* b_om = (const float*)d_in[30];
    const float* W_th = (const float*)d_in[31];
    const float* b_th = (const float*)d_in[32];
    const float* W_ph = (const float*)d_in[33];
    const float* b_ph = (const float*)d_in[34];

    float* ws     = (float*)d_ws;
    float* deg    = ws + OFF_DEG;
    float* pooled = ws + OFF_POOLED;
    float* wt     = ws + OFF_WT;
    float* h      = ws + OFF_H;

    hipMemsetAsync(deg, 0, 2 * NNODES * sizeof(float), stream);
    wt_transpose<<<6, 256, 0, stream>>>(W_pre1_a, W_pre2_a, W_gcn_a,
                                        W_pre1_b, W_pre2_b, W_gcn_b, wt);
    deg_kernel<<<2 * NEDGES / 256, 256, 0, stream>>>(ei_a, ea_a, ei_b, ea_b, deg);
    node_mlp<<<dim3(NNODES / 128, 2), 128, 0, stream>>>(x_a, x_b, wt,
                                                        b_pre1_a, b_pre2_a,
                                                        b_pre1_b, b_pre2_b, h);
    gcn_pool<<<dim3(NB, 4, 2), 256, 0, stream>>>(ei_a, ea_a, ei_b, ea_b,
                                                 deg, h, b_gcn_a, b_gcn_b, pooled);
    final_mlp<<<NB, 128, 0, stream>>>(pooled, linker,
                                      W_lin1, b_lin1, W_lin2, b_lin2, W_lin3, b_lin3,
                                      W_cb, b_cb, W_om, b_om, W_th, b_th, W_ph, b_ph,
                                      (float*)d_out);
}

// Round 2
// 1463.705 us; speedup vs baseline: 1.4731x; 1.4731x over previous
//
#include <hip/hip_runtime.h>
#include <hip/hip_bf16.h>

#define NNODES 131072
#define NEDGES 2097152
#define NB     128
#define NPG    1024   // nodes per graph
#define EPG    16384  // edges per graph

// ws layout in 4-byte units. Prefix (deg..h) matches the fallback path's needs.
#define OFF_DEG      0                                   // 2*NNODES floats
#define OFF_POOLED   (OFF_DEG + 2*NNODES)                // 2*NB*64
#define OFF_WT       (OFF_POOLED + 2*NB*64)              // 6*4096
#define OFF_H        (OFF_WT + 6*4096)                   // 2*NNODES*64
#define OFF_CNT      (OFF_H + (size_t)2*NNODES*64)       // 2*NNODES ints
#define OFF_ROWSTART (OFF_CNT + 2*NNODES)                // 2*NNODES ints
#define OFF_CURSOR   (OFF_ROWSTART + 2*NNODES)           // 2*NNODES ints
#define OFF_CSR      (OFF_CURSOR + 2*NNODES)             // 2*NEDGES float2 (as 4*NEDGES u32)
#define WS_NEEDED    ((OFF_CSR + (size_t)4*NEDGES) * 4)

// ---------------- transpose the six 64x64 node-MLP weights: wt[m][f][k] = W_m[k][f]
__global__ void wt_transpose(const float* __restrict__ w0, const float* __restrict__ w1,
                             const float* __restrict__ w2, const float* __restrict__ w3,
                             const float* __restrict__ w4, const float* __restrict__ w5,
                             float* __restrict__ wt) {
    int m = blockIdx.x;
    const float* w = (m == 0) ? w0 : (m == 1) ? w1 : (m == 2) ? w2
                   : (m == 3) ? w3 : (m == 4) ? w4 : w5;
    for (int idx = threadIdx.x; idx < 4096; idx += blockDim.x) {
        int f = idx >> 6, k = idx & 63;
        wt[m * 4096 + idx] = w[k * 64 + f];
    }
}

// ---------------- deg[n] = segment_sum(ew, dst); cnt[n] = in-degree (CSR path)
__global__ __launch_bounds__(256) void deg_cnt_kernel(
    const int* __restrict__ eia, const float* __restrict__ eaa,
    const int* __restrict__ eib, const float* __restrict__ eab,
    float* __restrict__ deg, int* __restrict__ cnt) {
    int i = blockIdx.x * 256 + threadIdx.x;          // 0 .. 2*NEDGES-1
    int br = (i >= NEDGES) ? 1 : 0;
    int e  = i - br * NEDGES;
    const int*   ei = br ? eib : eia;
    const float* ea = br ? eab : eaa;
    int dst = ei[NEDGES + e];
    unsafeAtomicAdd(&deg[br * NNODES + dst], ea[e]);
    atomicAdd(&cnt[br * NNODES + dst], 1);
}

// fallback-path deg only
__global__ __launch_bounds__(256) void deg_kernel(
    const int* __restrict__ eia, const float* __restrict__ eaa,
    const int* __restrict__ eib, const float* __restrict__ eab,
    float* __restrict__ deg) {
    int i = blockIdx.x * 256 + threadIdx.x;
    int br = (i >= NEDGES) ? 1 : 0;
    int e  = i - br * NEDGES;
    const int*   ei = br ? eib : eia;
    const float* ea = br ? eab : eaa;
    int dst = ei[NEDGES + e];
    unsafeAtomicAdd(&deg[br * NNODES + dst], ea[e]);
}

// ---------------- per-(graph,branch) exclusive scan of cnt -> rowstart, cursor
__global__ __launch_bounds__(256) void scan_kernel(const int* __restrict__ cnt,
                                                   int* __restrict__ rowstart,
                                                   int* __restrict__ cursor) {
    __shared__ int sm[256];
    const int gid = blockIdx.x;          // 0..255
    const int br  = gid >> 7;
    const int g   = gid & 127;
    const int t   = threadIdx.x;
    const int* c  = cnt + br * NNODES + g * NPG;
    int c0 = c[t * 4 + 0], c1 = c[t * 4 + 1], c2 = c[t * 4 + 2], c3 = c[t * 4 + 3];
    int T = c0 + c1 + c2 + c3;
    sm[t] = T;
    __syncthreads();
    for (int off = 1; off < 256; off <<= 1) {
        int v = (t >= off) ? sm[t - off] : 0;
        __syncthreads();
        sm[t] += v;
        __syncthreads();
    }
    int excl = sm[t] - T;
    int base = g * EPG + excl;   // within-branch global edge index space
    int* rs = rowstart + br * NNODES + g * NPG;
    int* cu = cursor   + br * NNODES + g * NPG;
    int r0 = base, r1 = base + c0, r2 = r1 + c1, r3 = r2 + c2;
    rs[t * 4 + 0] = r0; rs[t * 4 + 1] = r1; rs[t * 4 + 2] = r2; rs[t * 4 + 3] = r3;
    cu[t * 4 + 0] = r0; cu[t * 4 + 1] = r1; cu[t * 4 + 2] = r2; cu[t * 4 + 3] = r3;
}

// ---------------- fill CSR: csr[pos] = (src, norm)
__global__ __launch_bounds__(256) void fill_kernel(
    const int* __restrict__ eia, const float* __restrict__ eaa,
    const int* __restrict__ eib, const float* __restrict__ eab,
    const float* __restrict__ deg, int* __restrict__ cursor,
    float2* __restrict__ csr) {
    int i = blockIdx.x * 256 + threadIdx.x;
    int br = (i >= NEDGES) ? 1 : 0;
    int e  = i - br * NEDGES;
    const int*   ei = br ? eib : eia;
    const float* ea = br ? eab : eaa;
    int src = ei[e];
    int dst = ei[NEDGES + e];
    float w = ea[e];
    const float* dg = deg + br * NNODES;
    int pos = atomicAdd(&cursor[br * NNODES + dst], 1);
    float nrm = rsqrtf(dg[src] + 1.f) * w * rsqrtf(dg[dst] + 1.f);
    float2 pr;
    pr.x = __int_as_float(src);
    pr.y = nrm;
    csr[(size_t)br * NEDGES + pos] = pr;
}

// ---------------- fused 3-layer node MLP: h = relu(relu(x@W1+b1)@W2+b2)@Wg
__global__ __launch_bounds__(128) void node_mlp(
    const float* __restrict__ xa, const float* __restrict__ xb,
    const float* __restrict__ wt,
    const float* __restrict__ b1a, const float* __restrict__ b2a,
    const float* __restrict__ b1b, const float* __restrict__ b2b,
    float* __restrict__ hout) {
    __shared__ float bounce[128 * 65];
    const int br = blockIdx.y;
    const float* x   = br ? xb : xa;
    const float* wt1 = wt + br * 3 * 4096;
    const float* wt2 = wt1 + 4096;
    const float* wt3 = wt2 + 4096;
    const float* b1  = br ? b1b : b1a;
    const float* b2  = br ? b2b : b2a;
    const int node = blockIdx.x * 128 + threadIdx.x;

    float xr[64];
    const float4* xp = reinterpret_cast<const float4*>(x + (size_t)node * 64);
#pragma unroll
    for (int i = 0; i < 16; ++i) {
        float4 v = xp[i];
        xr[4 * i + 0] = v.x; xr[4 * i + 1] = v.y; xr[4 * i + 2] = v.z; xr[4 * i + 3] = v.w;
    }
    float* myrow = &bounce[threadIdx.x * 65];

    for (int f = 0; f < 64; ++f) {
        const float* w = wt1 + f * 64;
        float acc = b1[f];
#pragma unroll
        for (int k = 0; k < 64; ++k) acc = fmaf(xr[k], w[k], acc);
        myrow[f] = fmaxf(acc, 0.f);
    }
#pragma unroll
    for (int k = 0; k < 64; ++k) xr[k] = myrow[k];

    for (int f = 0; f < 64; ++f) {
        const float* w = wt2 + f * 64;
        float acc = b2[f];
#pragma unroll
        for (int k = 0; k < 64; ++k) acc = fmaf(xr[k], w[k], acc);
        myrow[f] = fmaxf(acc, 0.f);
    }
#pragma unroll
    for (int k = 0; k < 64; ++k) xr[k] = myrow[k];

    float* hp = hout + (size_t)br * NNODES * 64 + (size_t)node * 64;
    for (int f = 0; f < 64; ++f) {
        const float* w = wt3 + f * 64;
        float acc = 0.f;
#pragma unroll
        for (int k = 0; k < 64; ++k) acc = fmaf(xr[k], w[k], acc);
        hp[f] = acc;
    }
}

// ---------------- CSR gather GCN + self loop + bias + relu + graph-sum pool
// block = 256 threads = 4 waves; wave = 64 feature lanes; 16 nodes per wave.
__global__ __launch_bounds__(256) void gcn_gather_pool(
    const int* __restrict__ rowstart, const int* __restrict__ cnt,
    const float2* __restrict__ csr, const float* __restrict__ deg,
    const float* __restrict__ h,
    const float* __restrict__ bga, const float* __restrict__ bgb,
    float* __restrict__ pooled) {
    __shared__ float red[256];
    const int br   = blockIdx.y;
    const int wave = threadIdx.x >> 6;
    const int lane = threadIdx.x & 63;
    const int nblk = blockIdx.x;                 // 64 nodes per block
    const int n0   = nblk * 64 + wave * 16;
    const int g    = (nblk * 64) / NPG;
    const int*    rs = rowstart + br * NNODES;
    const int*    ct = cnt + br * NNODES;
    const float2* cs = csr + (size_t)br * NEDGES;
    const float*  dg = deg + br * NNODES;
    const float*  hh = h + (size_t)br * NNODES * 64;
    const float bias = (br ? bgb : bga)[lane];

    float psum = 0.f;
    for (int j = 0; j < 16; ++j) {
        int n = n0 + j;
        int r = rs[n];
        int c = ct[n];
        float acc = 0.f;
        float2 pr = (c > 0) ? cs[r] : make_float2(0.f, 0.f);
        for (int i = 0; i < c; ++i) {
            float2 nxt = (i + 1 < c) ? cs[r + i + 1] : pr;   // prefetch next pair
            int src = __float_as_int(pr.x);
            acc = fmaf(pr.y, hh[(size_t)src * 64 + lane], acc);
            pr = nxt;
        }
        float d = dg[n] + 1.f;
        float v = acc + hh[(size_t)n * 64 + lane] * (1.f / d) + bias;
        psum += fmaxf(v, 0.f);
    }
    red[threadIdx.x] = psum;
    __syncthreads();
    if (wave == 0) {
        float s = red[lane] + red[64 + lane] + red[128 + lane] + red[192 + lane];
        unsafeAtomicAdd(&pooled[br * (NB * 64) + g * 64 + lane], s);
    }
}

// ---------------- fallback: old fused scatter GCN (used only if ws too small)
__global__ __launch_bounds__(256) void gcn_pool(
    const int* __restrict__ eia, const float* __restrict__ eaa,
    const int* __restrict__ eib, const float* __restrict__ eab,
    const float* __restrict__ deg, const float* __restrict__ h,
    const float* __restrict__ bga, const float* __restrict__ bgb,
    float* __restrict__ pooled) {
    __shared__ float acc[NPG * 16];   // 64 KB
    const int g  = blockIdx.x;
    const int q  = blockIdx.y;
    const int br = blockIdx.z;
    const int*   ei = br ? eib : eia;
    const float* ea = br ? eab : eaa;
    const float* dg = deg + br * NNODES;
    const float* hh = h + (size_t)br * NNODES * 64;
    const float* bg = br ? bgb : bga;
    const int tid = threadIdx.x;

    for (int i = tid; i < NPG * 16; i += 256) acc[i] = 0.f;
    __syncthreads();

    const int f16   = tid & 15;
    const int es    = tid >> 4;
    const int fof   = q * 16 + f16;
    const int gnode = g * NPG;
    const int ebase = g * EPG;

#pragma unroll 2
    for (int it = 0; it < EPG / 16; ++it) {
        int e   = ebase + it * 16 + es;
        int src = ei[e];
        int dst = ei[NEDGES + e];
        float w = ea[e];
        float nrm = rsqrtf(dg[src] + 1.f) * w * rsqrtf(dg[dst] + 1.f);
        float hv  = hh[(size_t)src * 64 + fof];
        unsafeAtomicAdd(&acc[(dst - gnode) * 16 + f16], nrm * hv);
    }
    __syncthreads();

    float psum = 0.f;
    float bias = bg[fof];
    for (int n = es; n < NPG; n += 16) {
        float d = dg[gnode + n] + 1.f;
        float v = acc[n * 16 + f16] + hh[(size_t)(gnode + n) * 64 + fof] * (1.f / d) + bias;
        psum += fmaxf(v, 0.f);
    }
    __syncthreads();
    acc[tid] = psum;
    __syncthreads();
    if (tid < 16) {
        float s = 0.f;
#pragma unroll
        for (int j = 0; j < 16; ++j) s += acc[j * 16 + tid];
        pooled[br * (NB * 64) + g * 64 + q * 16 + tid] = s;
    }
}

// ---------------- final MLP heads
__global__ __launch_bounds__(128) void final_mlp(
    const float* __restrict__ pooled, const float* __restrict__ linker,
    const float* __restrict__ W1, const float* __restrict__ b1,
    const float* __restrict__ W2, const float* __restrict__ b2,
    const float* __restrict__ W3, const float* __restrict__ b3,
    const float* __restrict__ Wcb, const float* __restrict__ bcb,
    const float* __restrict__ Wom, const float* __restrict__ bom,
    const float* __restrict__ Wth, const float* __restrict__ bth,
    const float* __restrict__ Wph, const float* __restrict__ bph,
    float* __restrict__ out) {
    __shared__ float inv[260];
    __shared__ float x1[128];
    __shared__ float x2[64];
    const int g = blockIdx.x;
    const int t = threadIdx.x;
    if (t < 64) {
        float pa = pooled[g * 64 + t];
        float pb = pooled[NB * 64 + g * 64 + t];
        inv[t]       = pa;
        inv[64 + t]  = pa * (1.f / 1024.f);
        inv[128 + t] = pb;
        inv[192 + t] = pb * (1.f / 1024.f);
    }
    if (t == 0) inv[256] = linker[g];
    __syncthreads();

    {
        float a = b1[t];
        for (int i = 0; i < 257; ++i) a = fmaf(inv[i], W1[i * 128 + t], a);
        x1[t] = fmaxf(a, 0.f);
    }
    __syncthreads();
    if (t < 64) {
        float a = b2[t];
        for (int i = 0; i < 128; ++i) a = fmaf(x1[i], W2[i * 64 + t], a);
        x2[t] = fmaxf(a, 0.f);
    }
    __syncthreads();
    if (t < 8) {
        if (t == 0) {
            float a = b3[0];
            for (int i = 0; i < 64; ++i) a = fmaf(x2[i], W3[i], a);
            out[g] = a;
        } else if (t == 1) {
            float a = bcb[0];
            for (int i = 0; i < 64; ++i) a = fmaf(x2[i], Wcb[i], a);
            out[128 + g] = a;
        } else if (t < 4) {
            int j = t - 2; float a = bom[j];
            for (int i = 0; i < 64; ++i) a = fmaf(x2[i], Wom[i * 2 + j], a);
            out[256 + g * 2 + j] = a;
        } else if (t < 6) {
            int j = t - 4; float a = bth[j];
            for (int i = 0; i < 64; ++i) a = fmaf(x2[i], Wth[i * 2 + j], a);
            out[512 + g * 2 + j] = a;
        } else {
            int j = t - 6; float a = bph[j];
            for (int i = 0; i < 64; ++i) a = fmaf(x2[i], Wph[i * 2 + j], a);
            out[768 + g * 2 + j] = a;
        }
    }
}

extern "C" void kernel_launch(void* const* d_in, const int* in_sizes, int n_in,
                              void* d_out, int out_size, void* d_ws, size_t ws_size,
                              hipStream_t stream) {
    const float* x_a  = (const float*)d_in[0];
    const int*   ei_a = (const int*)d_in[1];
    const float* ea_a = (const float*)d_in[2];
    const float* x_b  = (const float*)d_in[4];
    const int*   ei_b = (const int*)d_in[5];
    const float* ea_b = (const float*)d_in[6];
    const float* linker = (const float*)d_in[8];
    const float* W_pre1_a = (const float*)d_in[9];
    const float* b_pre1_a = (const float*)d_in[10];
    const float* W_pre2_a = (const float*)d_in[11];
    const float* b_pre2_a = (const float*)d_in[12];
    const float* W_gcn_a  = (const float*)d_in[13];
    const float* b_gcn_a  = (const float*)d_in[14];
    const float* W_pre1_b = (const float*)d_in[15];
    const float* b_pre1_b = (const float*)d_in[16];
    const float* W_pre2_b = (const float*)d_in[17];
    const float* b_pre2_b = (const float*)d_in[18];
    const float* W_gcn_b  = (const float*)d_in[19];
    const float* b_gcn_b  = (const float*)d_in[20];
    const float* W_lin1 = (const float*)d_in[21];
    const float* b_lin1 = (const float*)d_in[22];
    const float* W_lin2 = (const float*)d_in[23];
    const float* b_lin2 = (const float*)d_in[24];
    const float* W_lin3 = (const float*)d_in[25];
    const float* b_lin3 = (const float*)d_in[26];
    const float* W_cb = (const float*)d_in[27];
    const float* b_cb = (const float*)d_in[28];
    const float* W_om = (const float*)d_in[29];
    const float* b_om = (const float*)d_in[30];
    const float* W_th = (const float*)d_in[31];
    const float* b_th = (const float*)d_in[32];
    const float* W_ph = (const float*)d_in[33];
    const float* b_ph = (const float*)d_in[34];

    float* ws     = (float*)d_ws;
    float* deg    = ws + OFF_DEG;
    float* pooled = ws + OFF_POOLED;
    float* wt     = ws + OFF_WT;
    float* h      = ws + OFF_H;
    int*   cnt      = (int*)(ws + OFF_CNT);
    int*   rowstart = (int*)(ws + OFF_ROWSTART);
    int*   cursor   = (int*)(ws + OFF_CURSOR);
    float2* csr     = (float2*)(ws + OFF_CSR);

    wt_transpose<<<6, 256, 0, stream>>>(W_pre1_a, W_pre2_a, W_gcn_a,
                                        W_pre1_b, W_pre2_b, W_gcn_b, wt);

    if (ws_size >= WS_NEEDED) {
        // CSR-gather path
        hipMemsetAsync(deg, 0, (2 * NNODES + 2 * NB * 64) * sizeof(float), stream); // deg + pooled
        hipMemsetAsync(cnt, 0, 2 * NNODES * sizeof(int), stream);
        deg_cnt_kernel<<<2 * NEDGES / 256, 256, 0, stream>>>(ei_a, ea_a, ei_b, ea_b, deg, cnt);
        scan_kernel<<<256, 256, 0, stream>>>(cnt, rowstart, cursor);
        fill_kernel<<<2 * NEDGES / 256, 256, 0, stream>>>(ei_a, ea_a, ei_b, ea_b,
                                                          deg, cursor, csr);
        node_mlp<<<dim3(NNODES / 128, 2), 128, 0, stream>>>(x_a, x_b, wt,
                                                            b_pre1_a, b_pre2_a,
                                                            b_pre1_b, b_pre2_b, h);
        gcn_gather_pool<<<dim3(NNODES / 64, 2), 256, 0, stream>>>(rowstart, cnt, csr, deg, h,
                                                                  b_gcn_a, b_gcn_b, pooled);
    } else {
        // fallback: old scatter path
        hipMemsetAsync(deg, 0, 2 * NNODES * sizeof(float), stream);
        deg_kernel<<<2 * NEDGES / 256, 256, 0, stream>>>(ei_a, ea_a, ei_b, ea_b, deg);
        node_mlp<<<dim3(NNODES / 128, 2), 128, 0, stream>>>(x_a, x_b, wt,
                                                            b_pre1_a, b_pre2_a,
                                                            b_pre1_b, b_pre2_b, h);
        gcn_pool<<<dim3(NB, 4, 2), 256, 0, stream>>>(ei_a, ea_a, ei_b, ea_b,
                                                     deg, h, b_gcn_a, b_gcn_b, pooled);
    }

    final_mlp<<<NB, 128, 0, stream>>>(pooled, linker,
                                      W_lin1, b_lin1, W_lin2, b_lin2, W_lin3, b_lin3,
                                      W_cb, b_cb, W_om, b_om, W_th, b_th, W_ph, b_ph,
                                      (float*)d_out);
}

// Round 3
// 1201.009 us; speedup vs baseline: 1.7953x; 1.2187x over previous
//
#include <hip/hip_runtime.h>
#include <hip/hip_bf16.h>

#define NNODES 131072
#define NEDGES 2097152
#define NB     128
#define NPG    1024   // nodes per graph
#define EPG    16384  // edges per graph

// ws layout in 4-byte units. Prefix (deg..h) matches the fallback path's needs.
#define OFF_DEG      0                                   // 2*NNODES floats
#define OFF_POOLED   (OFF_DEG + 2*NNODES)                // 2*NB*64
#define OFF_WT       (OFF_POOLED + 2*NB*64)              // 6*4096
#define OFF_H        (OFF_WT + 6*4096)                   // 2*NNODES*64
#define OFF_CNT      (OFF_H + (size_t)2*NNODES*64)       // 2*NNODES ints
#define OFF_ROWSTART (OFF_CNT + 2*NNODES)                // 2*NNODES ints
#define OFF_CURSOR   (OFF_ROWSTART + 2*NNODES)           // 2*NNODES ints
#define OFF_CSR      (OFF_CURSOR + 2*NNODES)             // 2*NEDGES float2 (as 4*NEDGES u32)
#define WS_NEEDED    ((OFF_CSR + (size_t)4*NEDGES) * 4)

// ---------------- transpose the six 64x64 node-MLP weights: wt[m][f][k] = W_m[k][f]
__global__ void wt_transpose(const float* __restrict__ w0, const float* __restrict__ w1,
                             const float* __restrict__ w2, const float* __restrict__ w3,
                             const float* __restrict__ w4, const float* __restrict__ w5,
                             float* __restrict__ wt) {
    int m = blockIdx.x;
    const float* w = (m == 0) ? w0 : (m == 1) ? w1 : (m == 2) ? w2
                   : (m == 3) ? w3 : (m == 4) ? w4 : w5;
    for (int idx = threadIdx.x; idx < 4096; idx += blockDim.x) {
        int f = idx >> 6, k = idx & 63;
        wt[m * 4096 + idx] = w[k * 64 + f];
    }
}

// ---------------- deg[n] = segment_sum(ew, dst); cnt[n] = in-degree (CSR path)
__global__ __launch_bounds__(256) void deg_cnt_kernel(
    const int* __restrict__ eia, const float* __restrict__ eaa,
    const int* __restrict__ eib, const float* __restrict__ eab,
    float* __restrict__ deg, int* __restrict__ cnt) {
    int i = blockIdx.x * 256 + threadIdx.x;          // 0 .. 2*NEDGES-1
    int br = (i >= NEDGES) ? 1 : 0;
    int e  = i - br * NEDGES;
    const int*   ei = br ? eib : eia;
    const float* ea = br ? eab : eaa;
    int dst = ei[NEDGES + e];
    unsafeAtomicAdd(&deg[br * NNODES + dst], ea[e]);
    atomicAdd(&cnt[br * NNODES + dst], 1);
}

// fallback-path deg only
__global__ __launch_bounds__(256) void deg_kernel(
    const int* __restrict__ eia, const float* __restrict__ eaa,
    const int* __restrict__ eib, const float* __restrict__ eab,
    float* __restrict__ deg) {
    int i = blockIdx.x * 256 + threadIdx.x;
    int br = (i >= NEDGES) ? 1 : 0;
    int e  = i - br * NEDGES;
    const int*   ei = br ? eib : eia;
    const float* ea = br ? eab : eaa;
    int dst = ei[NEDGES + e];
    unsafeAtomicAdd(&deg[br * NNODES + dst], ea[e]);
}

// ---------------- per-(graph,branch) exclusive scan of cnt -> rowstart, cursor
__global__ __launch_bounds__(256) void scan_kernel(const int* __restrict__ cnt,
                                                   int* __restrict__ rowstart,
                                                   int* __restrict__ cursor) {
    __shared__ int sm[256];
    const int gid = blockIdx.x;          // 0..255
    const int br  = gid >> 7;
    const int g   = gid & 127;
    const int t   = threadIdx.x;
    const int* c  = cnt + br * NNODES + g * NPG;
    int c0 = c[t * 4 + 0], c1 = c[t * 4 + 1], c2 = c[t * 4 + 2], c3 = c[t * 4 + 3];
    int T = c0 + c1 + c2 + c3;
    sm[t] = T;
    __syncthreads();
    for (int off = 1; off < 256; off <<= 1) {
        int v = (t >= off) ? sm[t - off] : 0;
        __syncthreads();
        sm[t] += v;
        __syncthreads();
    }
    int excl = sm[t] - T;
    int base = g * EPG + excl;   // within-branch global edge index space
    int* rs = rowstart + br * NNODES + g * NPG;
    int* cu = cursor   + br * NNODES + g * NPG;
    int r0 = base, r1 = base + c0, r2 = r1 + c1, r3 = r2 + c2;
    rs[t * 4 + 0] = r0; rs[t * 4 + 1] = r1; rs[t * 4 + 2] = r2; rs[t * 4 + 3] = r3;
    cu[t * 4 + 0] = r0; cu[t * 4 + 1] = r1; cu[t * 4 + 2] = r2; cu[t * 4 + 3] = r3;
}

// ---------------- fill CSR: csr[pos] = (src, norm)
__global__ __launch_bounds__(256) void fill_kernel(
    const int* __restrict__ eia, const float* __restrict__ eaa,
    const int* __restrict__ eib, const float* __restrict__ eab,
    const float* __restrict__ deg, int* __restrict__ cursor,
    float2* __restrict__ csr) {
    int i = blockIdx.x * 256 + threadIdx.x;
    int br = (i >= NEDGES) ? 1 : 0;
    int e  = i - br * NEDGES;
    const int*   ei = br ? eib : eia;
    const float* ea = br ? eab : eaa;
    int src = ei[e];
    int dst = ei[NEDGES + e];
    float w = ea[e];
    const float* dg = deg + br * NNODES;
    int pos = atomicAdd(&cursor[br * NNODES + dst], 1);
    float nrm = rsqrtf(dg[src] + 1.f) * w * rsqrtf(dg[dst] + 1.f);
    float2 pr;
    pr.x = __int_as_float(src);
    pr.y = nrm;
    csr[(size_t)br * NEDGES + pos] = pr;
}

// ---------------- fused 3-layer node MLP: h = relu(relu(x@W1+b1)@W2+b2)@Wg
__global__ __launch_bounds__(128) void node_mlp(
    const float* __restrict__ xa, const float* __restrict__ xb,
    const float* __restrict__ wt,
    const float* __restrict__ b1a, const float* __restrict__ b2a,
    const float* __restrict__ b1b, const float* __restrict__ b2b,
    float* __restrict__ hout) {
    __shared__ float bounce[128 * 65];
    const int br = blockIdx.y;
    const float* x   = br ? xb : xa;
    const float* wt1 = wt + br * 3 * 4096;
    const float* wt2 = wt1 + 4096;
    const float* wt3 = wt2 + 4096;
    const float* b1  = br ? b1b : b1a;
    const float* b2  = br ? b2b : b2a;
    const int node = blockIdx.x * 128 + threadIdx.x;

    float xr[64];
    const float4* xp = reinterpret_cast<const float4*>(x + (size_t)node * 64);
#pragma unroll
    for (int i = 0; i < 16; ++i) {
        float4 v = xp[i];
        xr[4 * i + 0] = v.x; xr[4 * i + 1] = v.y; xr[4 * i + 2] = v.z; xr[4 * i + 3] = v.w;
    }
    float* myrow = &bounce[threadIdx.x * 65];

#pragma unroll 2
    for (int f = 0; f < 64; ++f) {
        const float* w = wt1 + f * 64;
        float acc = b1[f];
#pragma unroll
        for (int k = 0; k < 64; ++k) acc = fmaf(xr[k], w[k], acc);
        myrow[f] = fmaxf(acc, 0.f);
    }
#pragma unroll
    for (int k = 0; k < 64; ++k) xr[k] = myrow[k];

#pragma unroll 2
    for (int f = 0; f < 64; ++f) {
        const float* w = wt2 + f * 64;
        float acc = b2[f];
#pragma unroll
        for (int k = 0; k < 64; ++k) acc = fmaf(xr[k], w[k], acc);
        myrow[f] = fmaxf(acc, 0.f);
    }
#pragma unroll
    for (int k = 0; k < 64; ++k) xr[k] = myrow[k];

    float* hp = hout + (size_t)br * NNODES * 64 + (size_t)node * 64;
#pragma unroll 2
    for (int f = 0; f < 64; ++f) {
        const float* w = wt3 + f * 64;
        float acc = 0.f;
#pragma unroll
        for (int k = 0; k < 64; ++k) acc = fmaf(xr[k], w[k], acc);
        hp[f] = acc;
    }
}

// ---------------- CSR gather GCN + self loop + bias + relu + graph-sum pool
// 4096 flat blocks; bid&7 = XCD (dispatch round-robin); each XCD owns 32
// graph-branch pairs so one graph's h working set (256KB) stays in one L2.
// wave = 64 feature lanes; 16 nodes per wave; 4-way edge ILP.
__global__ __launch_bounds__(256) void gcn_gather_pool(
    const int* __restrict__ rowstart, const int* __restrict__ cnt,
    const float2* __restrict__ csr, const float* __restrict__ deg,
    const float* __restrict__ h,
    const float* __restrict__ bga, const float* __restrict__ bgb,
    float* __restrict__ pooled) {
    __shared__ float red[256];
    const int bid  = blockIdx.x;
    const int xcd  = bid & 7;
    const int sub  = bid >> 3;                  // 0..511
    const int gb   = xcd * 32 + (sub >> 4);     // graph-branch pair 0..255
    const int blk  = sub & 15;                  // 16 blocks x 64 nodes per graph
    const int br   = gb >> 7;
    const int g    = gb & 127;
    const int wave = threadIdx.x >> 6;
    const int lane = threadIdx.x & 63;
    const int n0   = g * NPG + blk * 64 + wave * 16;

    const int*    rs = rowstart + br * NNODES;
    const int*    ct = cnt + br * NNODES;
    const float2* cs = csr + (size_t)br * NEDGES;
    const float*  dg = deg + br * NNODES;
    const float*  hh = h + (size_t)br * NNODES * 64;
    const float bias = (br ? bgb : bga)[lane];

    float psum = 0.f;
    for (int j = 0; j < 16; ++j) {
        int n = n0 + j;
        int r = __builtin_amdgcn_readfirstlane(rs[n]);
        int c = __builtin_amdgcn_readfirstlane(ct[n]);
        float a0 = 0.f, a1 = 0.f, a2 = 0.f, a3 = 0.f;
        int i = 0;
        for (; i + 4 <= c; i += 4) {
            float2 p0 = cs[r + i + 0];
            float2 p1 = cs[r + i + 1];
            float2 p2 = cs[r + i + 2];
            float2 p3 = cs[r + i + 3];
            a0 = fmaf(p0.y, hh[(size_t)__float_as_int(p0.x) * 64 + lane], a0);
            a1 = fmaf(p1.y, hh[(size_t)__float_as_int(p1.x) * 64 + lane], a1);
            a2 = fmaf(p2.y, hh[(size_t)__float_as_int(p2.x) * 64 + lane], a2);
            a3 = fmaf(p3.y, hh[(size_t)__float_as_int(p3.x) * 64 + lane], a3);
        }
        for (; i < c; ++i) {
            float2 p = cs[r + i];
            a0 = fmaf(p.y, hh[(size_t)__float_as_int(p.x) * 64 + lane], a0);
        }
        float d = dg[n] + 1.f;
        float v = (a0 + a1) + (a2 + a3) + hh[(size_t)n * 64 + lane] * (1.f / d) + bias;
        psum += fmaxf(v, 0.f);
    }
    red[threadIdx.x] = psum;
    __syncthreads();
    if (wave == 0) {
        float s = red[lane] + red[64 + lane] + red[128 + lane] + red[192 + lane];
        unsafeAtomicAdd(&pooled[br * (NB * 64) + g * 64 + lane], s);
    }
}

// ---------------- fallback: old fused scatter GCN (used only if ws too small)
__global__ __launch_bounds__(256) void gcn_pool(
    const int* __restrict__ eia, const float* __restrict__ eaa,
    const int* __restrict__ eib, const float* __restrict__ eab,
    const float* __restrict__ deg, const float* __restrict__ h,
    const float* __restrict__ bga, const float* __restrict__ bgb,
    float* __restrict__ pooled) {
    __shared__ float acc[NPG * 16];   // 64 KB
    const int g  = blockIdx.x;
    const int q  = blockIdx.y;
    const int br = blockIdx.z;
    const int*   ei = br ? eib : eia;
    const float* ea = br ? eab : eaa;
    const float* dg = deg + br * NNODES;
    const float* hh = h + (size_t)br * NNODES * 64;
    const float* bg = br ? bgb : bga;
    const int tid = threadIdx.x;

    for (int i = tid; i < NPG * 16; i += 256) acc[i] = 0.f;
    __syncthreads();

    const int f16   = tid & 15;
    const int es    = tid >> 4;
    const int fof   = q * 16 + f16;
    const int gnode = g * NPG;
    const int ebase = g * EPG;

#pragma unroll 2
    for (int it = 0; it < EPG / 16; ++it) {
        int e   = ebase + it * 16 + es;
        int src = ei[e];
        int dst = ei[NEDGES + e];
        float w = ea[e];
        float nrm = rsqrtf(dg[src] + 1.f) * w * rsqrtf(dg[dst] + 1.f);
        float hv  = hh[(size_t)src * 64 + fof];
        unsafeAtomicAdd(&acc[(dst - gnode) * 16 + f16], nrm * hv);
    }
    __syncthreads();

    float psum = 0.f;
    float bias = bg[fof];
    for (int n = es; n < NPG; n += 16) {
        float d = dg[gnode + n] + 1.f;
        float v = acc[n * 16 + f16] + hh[(size_t)(gnode + n) * 64 + fof] * (1.f / d) + bias;
        psum += fmaxf(v, 0.f);
    }
    __syncthreads();
    acc[tid] = psum;
    __syncthreads();
    if (tid < 16) {
        float s = 0.f;
#pragma unroll
        for (int j = 0; j < 16; ++j) s += acc[j * 16 + tid];
        pooled[br * (NB * 64) + g * 64 + q * 16 + tid] = s;
    }
}

// ---------------- final MLP heads
__global__ __launch_bounds__(128) void final_mlp(
    const float* __restrict__ pooled, const float* __restrict__ linker,
    const float* __restrict__ W1, const float* __restrict__ b1,
    const float* __restrict__ W2, const float* __restrict__ b2,
    const float* __restrict__ W3, const float* __restrict__ b3,
    const float* __restrict__ Wcb, const float* __restrict__ bcb,
    const float* __restrict__ Wom, const float* __restrict__ bom,
    const float* __restrict__ Wth, const float* __restrict__ bth,
    const float* __restrict__ Wph, const float* __restrict__ bph,
    float* __restrict__ out) {
    __shared__ float inv[260];
    __shared__ float x1[128];
    __shared__ float x2[64];
    const int g = blockIdx.x;
    const int t = threadIdx.x;
    if (t < 64) {
        float pa = pooled[g * 64 + t];
        float pb = pooled[NB * 64 + g * 64 + t];
        inv[t]       = pa;
        inv[64 + t]  = pa * (1.f / 1024.f);
        inv[128 + t] = pb;
        inv[192 + t] = pb * (1.f / 1024.f);
    }
    if (t == 0) inv[256] = linker[g];
    __syncthreads();

    {
        float a = b1[t];
        for (int i = 0; i < 257; ++i) a = fmaf(inv[i], W1[i * 128 + t], a);
        x1[t] = fmaxf(a, 0.f);
    }
    __syncthreads();
    if (t < 64) {
        float a = b2[t];
        for (int i = 0; i < 128; ++i) a = fmaf(x1[i], W2[i * 64 + t], a);
        x2[t] = fmaxf(a, 0.f);
    }
    __syncthreads();
    if (t < 8) {
        if (t == 0) {
            float a = b3[0];
            for (int i = 0; i < 64; ++i) a = fmaf(x2[i], W3[i], a);
            out[g] = a;
        } else if (t == 1) {
            float a = bcb[0];
            for (int i = 0; i < 64; ++i) a = fmaf(x2[i], Wcb[i], a);
            out[128 + g] = a;
        } else if (t < 4) {
            int j = t - 2; float a = bom[j];
            for (int i = 0; i < 64; ++i) a = fmaf(x2[i], Wom[i * 2 + j], a);
            out[256 + g * 2 + j] = a;
        } else if (t < 6) {
            int j = t - 4; float a = bth[j];
            for (int i = 0; i < 64; ++i) a = fmaf(x2[i], Wth[i * 2 + j], a);
            out[512 + g * 2 + j] = a;
        } else {
            int j = t - 6; float a = bph[j];
            for (int i = 0; i < 64; ++i) a = fmaf(x2[i], Wph[i * 2 + j], a);
            out[768 + g * 2 + j] = a;
        }
    }
}

extern "C" void kernel_launch(void* const* d_in, const int* in_sizes, int n_in,
                              void* d_out, int out_size, void* d_ws, size_t ws_size,
                              hipStream_t stream) {
    const float* x_a  = (const float*)d_in[0];
    const int*   ei_a = (const int*)d_in[1];
    const float* ea_a = (const float*)d_in[2];
    const float* x_b  = (const float*)d_in[4];
    const int*   ei_b = (const int*)d_in[5];
    const float* ea_b = (const float*)d_in[6];
    const float* linker = (const float*)d_in[8];
    const float* W_pre1_a = (const float*)d_in[9];
    const float* b_pre1_a = (const float*)d_in[10];
    const float* W_pre2_a = (const float*)d_in[11];
    const float* b_pre2_a = (const float*)d_in[12];
    const float* W_gcn_a  = (const float*)d_in[13];
    const float* b_gcn_a  = (const float*)d_in[14];
    const float* W_pre1_b = (const float*)d_in[15];
    const float* b_pre1_b = (const float*)d_in[16];
    const float* W_pre2_b = (const float*)d_in[17];
    const float* b_pre2_b = (const float*)d_in[18];
    const float* W_gcn_b  = (const float*)d_in[19];
    const float* b_gcn_b  = (const float*)d_in[20];
    const float* W_lin1 = (const float*)d_in[21];
    const float* b_lin1 = (const float*)d_in[22];
    const float* W_lin2 = (const float*)d_in[23];
    const float* b_lin2 = (const float*)d_in[24];
    const float* W_lin3 = (const float*)d_in[25];
    const float* b_lin3 = (const float*)d_in[26];
    const float* W_cb = (const float*)d_in[27];
    const float* b_cb = (const float*)d_in[28];
    const float* W_om = (const float*)d_in[29];
    const float* b_om = (const float*)d_in[30];
    const float* W_th = (const float*)d_in[31];
    const float* b_th = (const float*)d_in[32];
    const float* W_ph = (const float*)d_in[33];
    const float* b_ph = (const float*)d_in[34];

    float* ws     = (float*)d_ws;
    float* deg    = ws + OFF_DEG;
    float* pooled = ws + OFF_POOLED;
    float* wt     = ws + OFF_WT;
    float* h      = ws + OFF_H;
    int*   cnt      = (int*)(ws + OFF_CNT);
    int*   rowstart = (int*)(ws + OFF_ROWSTART);
    int*   cursor   = (int*)(ws + OFF_CURSOR);
    float2* csr     = (float2*)(ws + OFF_CSR);

    wt_transpose<<<6, 256, 0, stream>>>(W_pre1_a, W_pre2_a, W_gcn_a,
                                        W_pre1_b, W_pre2_b, W_gcn_b, wt);

    if (ws_size >= WS_NEEDED) {
        // CSR-gather path
        hipMemsetAsync(deg, 0, (2 * NNODES + 2 * NB * 64) * sizeof(float), stream); // deg + pooled
        hipMemsetAsync(cnt, 0, 2 * NNODES * sizeof(int), stream);
        deg_cnt_kernel<<<2 * NEDGES / 256, 256, 0, stream>>>(ei_a, ea_a, ei_b, ea_b, deg, cnt);
        scan_kernel<<<256, 256, 0, stream>>>(cnt, rowstart, cursor);
        fill_kernel<<<2 * NEDGES / 256, 256, 0, stream>>>(ei_a, ea_a, ei_b, ea_b,
                                                          deg, cursor, csr);
        node_mlp<<<dim3(NNODES / 128, 2), 128, 0, stream>>>(x_a, x_b, wt,
                                                            b_pre1_a, b_pre2_a,
                                                            b_pre1_b, b_pre2_b, h);
        gcn_gather_pool<<<4096, 256, 0, stream>>>(rowstart, cnt, csr, deg, h,
                                                  b_gcn_a, b_gcn_b, pooled);
    } else {
        // fallback: old scatter path
        hipMemsetAsync(deg, 0, 2 * NNODES * sizeof(float), stream);
        deg_kernel<<<2 * NEDGES / 256, 256, 0, stream>>>(ei_a, ea_a, ei_b, ea_b, deg);
        node_mlp<<<dim3(NNODES / 128, 2), 128, 0, stream>>>(x_a, x_b, wt,
                                                            b_pre1_a, b_pre2_a,
                                                            b_pre1_b, b_pre2_b, h);
        gcn_pool<<<dim3(NB, 4, 2), 256, 0, stream>>>(ei_a, ea_a, ei_b, ea_b,
                                                     deg, h, b_gcn_a, b_gcn_b, pooled);
    }

    final_mlp<<<NB, 128, 0, stream>>>(pooled, linker,
                                      W_lin1, b_lin1, W_lin2, b_lin2, W_lin3, b_lin3,
                                      W_cb, b_cb, W_om, b_om, W_th, b_th, W_ph, b_ph,
                                      (float*)d_out);
}

// Round 5
// 742.466 us; speedup vs baseline: 2.9040x; 1.6176x over previous
//
#include <hip/hip_runtime.h>
#include <hip/hip_bf16.h>

#define NNODES 131072
#define NEDGES 2097152
#define NB     128
#define NPG    1024   // nodes per graph
#define EPG    16384  // edges per graph

// ws layout in 4-byte units. Prefix (deg..h) matches the fallback path's needs.
#define OFF_DEG      0                                   // 2*NNODES floats
#define OFF_POOLED   (OFF_DEG + 2*NNODES)                // 2*NB*64
#define OFF_WT       (OFF_POOLED + 2*NB*64)              // 96 KB: wfrag (main) / wt (fallback)
#define OFF_H        (OFF_WT + 6*4096)                   // 2*NNODES*64
#define OFF_CNT      (OFF_H + (size_t)2*NNODES*64)       // 2*NNODES ints
#define OFF_ROWSTART (OFF_CNT + 2*NNODES)                // 2*NNODES ints
#define OFF_CURSOR   (OFF_ROWSTART + 2*NNODES)           // 2*NNODES ints
#define OFF_CSR      (OFF_CURSOR + 2*NNODES)             // 2*NEDGES float2
#define WS_NEEDED    ((OFF_CSR + (size_t)4*NEDGES) * 4)

typedef __attribute__((ext_vector_type(8))) short bfrag;
typedef __attribute__((ext_vector_type(4))) float f32x4;

__device__ __forceinline__ unsigned short f2bf(float v) {
    unsigned int u = __float_as_uint(v);
    unsigned int r = (u + 0x7fffu + ((u >> 16) & 1u)) >> 16;
    return (unsigned short)r;
}
__device__ __forceinline__ float bf2f(unsigned short s) {
    return __uint_as_float(((unsigned int)s) << 16);
}

// ---------------- pack six 64x64 weights into split-bf16 MFMA B-fragments.
// Layout per matrix m: [hi/lo(2)][ft(4)][kt(2)][lane(64)][i(8)] ushort.
// k-convention (MUST match the A-side assembly in node_mlp_mfma — the same
// sigma on both sides makes the intra-fragment map cancel for any true HW
// layout, since HW A/B k-distributions share one (lane,i) functional form):
//   col f = ft*16 + (lane&15);   k = kt*32 + (lane>>4)*8 + i     [contiguous-8]
__global__ void wprep(const float* __restrict__ w0, const float* __restrict__ w1,
                      const float* __restrict__ w2, const float* __restrict__ w3,
                      const float* __restrict__ w4, const float* __restrict__ w5,
                      unsigned short* __restrict__ wf) {
    int m = blockIdx.x;
    const float* w = (m == 0) ? w0 : (m == 1) ? w1 : (m == 2) ? w2
                   : (m == 3) ? w3 : (m == 4) ? w4 : w5;
    for (int idx = threadIdx.x; idx < 4096; idx += blockDim.x) {
        int ft   = idx >> 10;
        int kt   = (idx >> 9) & 1;
        int lane = (idx >> 3) & 63;
        int i    = idx & 7;
        int f = ft * 16 + (lane & 15);
        int k = kt * 32 + ((lane >> 4) << 3) + i;     // contiguous-8 (matches A side)
        float v = w[k * 64 + f];
        unsigned short hi = f2bf(v);
        unsigned short lo = f2bf(v - bf2f(hi));
        wf[m * 8192 + idx]        = hi;
        wf[m * 8192 + 4096 + idx] = lo;
    }
}

// ---------------- deg[n] = segment_sum(ew, dst); cnt[n] = in-degree (CSR path)
__global__ __launch_bounds__(256) void deg_cnt_kernel(
    const int* __restrict__ eia, const float* __restrict__ eaa,
    const int* __restrict__ eib, const float* __restrict__ eab,
    float* __restrict__ deg, int* __restrict__ cnt) {
    int i = blockIdx.x * 256 + threadIdx.x;          // 0 .. 2*NEDGES-1
    int br = (i >= NEDGES) ? 1 : 0;
    int e  = i - br * NEDGES;
    const int*   ei = br ? eib : eia;
    const float* ea = br ? eab : eaa;
    int dst = ei[NEDGES + e];
    unsafeAtomicAdd(&deg[br * NNODES + dst], ea[e]);
    atomicAdd(&cnt[br * NNODES + dst], 1);
}

// fallback-path deg only
__global__ __launch_bounds__(256) void deg_kernel(
    const int* __restrict__ eia, const float* __restrict__ eaa,
    const int* __restrict__ eib, const float* __restrict__ eab,
    float* __restrict__ deg) {
    int i = blockIdx.x * 256 + threadIdx.x;
    int br = (i >= NEDGES) ? 1 : 0;
    int e  = i - br * NEDGES;
    const int*   ei = br ? eib : eia;
    const float* ea = br ? eab : eaa;
    int dst = ei[NEDGES + e];
    unsafeAtomicAdd(&deg[br * NNODES + dst], ea[e]);
}

// ---------------- per-(graph,branch) exclusive scan of cnt -> rowstart, cursor
__global__ __launch_bounds__(256) void scan_kernel(const int* __restrict__ cnt,
                                                   int* __restrict__ rowstart,
                                                   int* __restrict__ cursor) {
    __shared__ int sm[256];
    const int gid = blockIdx.x;          // 0..255
    const int br  = gid >> 7;
    const int g   = gid & 127;
    const int t   = threadIdx.x;
    const int* c  = cnt + br * NNODES + g * NPG;
    int c0 = c[t * 4 + 0], c1 = c[t * 4 + 1], c2 = c[t * 4 + 2], c3 = c[t * 4 + 3];
    int T = c0 + c1 + c2 + c3;
    sm[t] = T;
    __syncthreads();
    for (int off = 1; off < 256; off <<= 1) {
        int v = (t >= off) ? sm[t - off] : 0;
        __syncthreads();
        sm[t] += v;
        __syncthreads();
    }
    int excl = sm[t] - T;
    int base = g * EPG + excl;
    int* rs = rowstart + br * NNODES + g * NPG;
    int* cu = cursor   + br * NNODES + g * NPG;
    int r0 = base, r1 = base + c0, r2 = r1 + c1, r3 = r2 + c2;
    rs[t * 4 + 0] = r0; rs[t * 4 + 1] = r1; rs[t * 4 + 2] = r2; rs[t * 4 + 3] = r3;
    cu[t * 4 + 0] = r0; cu[t * 4 + 1] = r1; cu[t * 4 + 2] = r2; cu[t * 4 + 3] = r3;
}

// ---------------- fill CSR: csr[pos] = (src, norm)
__global__ __launch_bounds__(256) void fill_kernel(
    const int* __restrict__ eia, const float* __restrict__ eaa,
    const int* __restrict__ eib, const float* __restrict__ eab,
    const float* __restrict__ deg, int* __restrict__ cursor,
    float2* __restrict__ csr) {
    int i = blockIdx.x * 256 + threadIdx.x;
    int br = (i >= NEDGES) ? 1 : 0;
    int e  = i - br * NEDGES;
    const int*   ei = br ? eib : eia;
    const float* ea = br ? eab : eaa;
    int src = ei[e];
    int dst = ei[NEDGES + e];
    float w = ea[e];
    const float* dg = deg + br * NNODES;
    int pos = atomicAdd(&cursor[br * NNODES + dst], 1);
    float nrm = rsqrtf(dg[src] + 1.f) * w * rsqrtf(dg[dst] + 1.f);
    float2 pr;
    pr.x = __int_as_float(src);
    pr.y = nrm;
    csr[(size_t)br * NEDGES + pos] = pr;
}

// ---------------- MFMA node MLP: h = relu(relu(x@W1+b1)@W2+b2)@Wg
// Split-bf16 (hi/lo): x*W ~= xh*Wh + xl*Wh + xh*Wl (error ~2^-18 rel).
// wave = 16 nodes; per layer 4 ft * 2 kt * 3 terms = 24 mfma 16x16x32.
// A-side k-convention: k = kt*32 + (lane>>4)*8 + i  (contiguous-8; == wprep).
__global__ __launch_bounds__(256) void node_mlp_mfma(
    const float* __restrict__ xa, const float* __restrict__ xb,
    const unsigned short* __restrict__ wf,
    const float* __restrict__ b1a, const float* __restrict__ b2a,
    const float* __restrict__ b1b, const float* __restrict__ b2b,
    float* __restrict__ hout) {
    __shared__ float lds[4 * 16 * 65];
    const int br = blockIdx.y;
    const float* x = br ? xb : xa;
    const unsigned short* wfb = wf + br * 3 * 8192;
    const float* b1 = br ? b1b : b1a;
    const float* b2 = br ? b2b : b2a;
    const int wave = threadIdx.x >> 6;
    const int lane = threadIdx.x & 63;
    const int row  = lane & 15;    // A row / B col / C col index
    const int kg   = lane >> 4;
    const int n0   = blockIdx.x * 64 + wave * 16;
    float* wlds = &lds[wave * 16 * 65];

    // ---- A-frags for layer 1 directly from x (8 consecutive floats per kt)
    bfrag ahi[2], alo[2];
#pragma unroll
    for (int kt = 0; kt < 2; ++kt) {
        const float4* p = reinterpret_cast<const float4*>(
            x + (size_t)(n0 + row) * 64 + kt * 32 + kg * 8);
        float4 v0 = p[0], v1 = p[1];
        float vv[8] = {v0.x, v0.y, v0.z, v0.w, v1.x, v1.y, v1.z, v1.w};
        bfrag h, l;
#pragma unroll
        for (int i = 0; i < 8; ++i) {
            unsigned short hb = f2bf(vv[i]);
            unsigned short lb = f2bf(vv[i] - bf2f(hb));
            h[i] = (short)hb;
            l[i] = (short)lb;
        }
        ahi[kt] = h; alo[kt] = l;
    }

#pragma unroll
    for (int layer = 0; layer < 3; ++layer) {
        const unsigned short* wl = wfb + layer * 8192;
        bfrag bhi[4][2], blo[4][2];
#pragma unroll
        for (int ft = 0; ft < 4; ++ft)
#pragma unroll
            for (int kt = 0; kt < 2; ++kt) {
                bhi[ft][kt] = *reinterpret_cast<const bfrag*>(wl + ft * 1024 + kt * 512 + lane * 8);
                blo[ft][kt] = *reinterpret_cast<const bfrag*>(wl + 4096 + ft * 1024 + kt * 512 + lane * 8);
            }
        f32x4 acc[4];
#pragma unroll
        for (int ft = 0; ft < 4; ++ft) {
            float bv = (layer == 0) ? b1[ft * 16 + row]
                     : (layer == 1) ? b2[ft * 16 + row] : 0.f;
            acc[ft] = (f32x4){bv, bv, bv, bv};
        }
#pragma unroll
        for (int ft = 0; ft < 4; ++ft)
#pragma unroll
            for (int kt = 0; kt < 2; ++kt) {
                acc[ft] = __builtin_amdgcn_mfma_f32_16x16x32_bf16(ahi[kt], bhi[ft][kt], acc[ft], 0, 0, 0);
                acc[ft] = __builtin_amdgcn_mfma_f32_16x16x32_bf16(alo[kt], bhi[ft][kt], acc[ft], 0, 0, 0);
                acc[ft] = __builtin_amdgcn_mfma_f32_16x16x32_bf16(ahi[kt], blo[ft][kt], acc[ft], 0, 0, 0);
            }

        if (layer < 2) {
            // relu -> LDS bounce (C layout: node=kg*4+r, feat=ft*16+row)
#pragma unroll
            for (int ft = 0; ft < 4; ++ft)
#pragma unroll
                for (int r = 0; r < 4; ++r)
                    wlds[(kg * 4 + r) * 65 + ft * 16 + row] = fmaxf(acc[ft][r], 0.f);
            __syncthreads();
            // re-read in A layout (8 consecutive feats of own node-row)
#pragma unroll
            for (int kt = 0; kt < 2; ++kt) {
                const float* rp = &wlds[row * 65 + kt * 32 + kg * 8];
                bfrag h, l;
#pragma unroll
                for (int i = 0; i < 8; ++i) {
                    float v = rp[i];
                    unsigned short hb = f2bf(v);
                    unsigned short lb = f2bf(v - bf2f(hb));
                    h[i] = (short)hb;
                    l[i] = (short)lb;
                }
                ahi[kt] = h; alo[kt] = l;
            }
            __syncthreads();
        } else {
            float* hp = hout + (size_t)br * NNODES * 64 + (size_t)n0 * 64;
#pragma unroll
            for (int ft = 0; ft < 4; ++ft)
#pragma unroll
                for (int r = 0; r < 4; ++r)
                    hp[(kg * 4 + r) * 64 + ft * 16 + row] = acc[ft][r];
        }
    }
}

// ---------------- fallback node MLP (ws too small): scalar path + wt transpose
__global__ void wt_transpose(const float* __restrict__ w0, const float* __restrict__ w1,
                             const float* __restrict__ w2, const float* __restrict__ w3,
                             const float* __restrict__ w4, const float* __restrict__ w5,
                             float* __restrict__ wt) {
    int m = blockIdx.x;
    const float* w = (m == 0) ? w0 : (m == 1) ? w1 : (m == 2) ? w2
                   : (m == 3) ? w3 : (m == 4) ? w4 : w5;
    for (int idx = threadIdx.x; idx < 4096; idx += blockDim.x) {
        int f = idx >> 6, k = idx & 63;
        wt[m * 4096 + idx] = w[k * 64 + f];
    }
}

__global__ __launch_bounds__(128) void node_mlp(
    const float* __restrict__ xa, const float* __restrict__ xb,
    const float* __restrict__ wt,
    const float* __restrict__ b1a, const float* __restrict__ b2a,
    const float* __restrict__ b1b, const float* __restrict__ b2b,
    float* __restrict__ hout) {
    __shared__ float bounce[128 * 65];
    const int br = blockIdx.y;
    const float* x   = br ? xb : xa;
    const float* wt1 = wt + br * 3 * 4096;
    const float* wt2 = wt1 + 4096;
    const float* wt3 = wt2 + 4096;
    const float* b1  = br ? b1b : b1a;
    const float* b2  = br ? b2b : b2a;
    const int node = blockIdx.x * 128 + threadIdx.x;

    float xr[64];
    const float4* xp = reinterpret_cast<const float4*>(x + (size_t)node * 64);
#pragma unroll
    for (int i = 0; i < 16; ++i) {
        float4 v = xp[i];
        xr[4 * i + 0] = v.x; xr[4 * i + 1] = v.y; xr[4 * i + 2] = v.z; xr[4 * i + 3] = v.w;
    }
    float* myrow = &bounce[threadIdx.x * 65];

    for (int f = 0; f < 64; ++f) {
        const float* w = wt1 + f * 64;
        float acc = b1[f];
#pragma unroll
        for (int k = 0; k < 64; ++k) acc = fmaf(xr[k], w[k], acc);
        myrow[f] = fmaxf(acc, 0.f);
    }
#pragma unroll
    for (int k = 0; k < 64; ++k) xr[k] = myrow[k];

    for (int f = 0; f < 64; ++f) {
        const float* w = wt2 + f * 64;
        float acc = b2[f];
#pragma unroll
        for (int k = 0; k < 64; ++k) acc = fmaf(xr[k], w[k], acc);
        myrow[f] = fmaxf(acc, 0.f);
    }
#pragma unroll
    for (int k = 0; k < 64; ++k) xr[k] = myrow[k];

    float* hp = hout + (size_t)br * NNODES * 64 + (size_t)node * 64;
    for (int f = 0; f < 64; ++f) {
        const float* w = wt3 + f * 64;
        float acc = 0.f;
#pragma unroll
        for (int k = 0; k < 64; ++k) acc = fmaf(xr[k], w[k], acc);
        hp[f] = acc;
    }
}

// ---------------- CSR gather GCN + self loop + bias + relu + graph-sum pool
__global__ __launch_bounds__(256) void gcn_gather_pool(
    const int* __restrict__ rowstart, const int* __restrict__ cnt,
    const float2* __restrict__ csr, const float* __restrict__ deg,
    const float* __restrict__ h,
    const float* __restrict__ bga, const float* __restrict__ bgb,
    float* __restrict__ pooled) {
    __shared__ float red[256];
    const int bid  = blockIdx.x;
    const int xcd  = bid & 7;
    const int sub  = bid >> 3;                  // 0..511
    const int gb   = xcd * 32 + (sub >> 4);     // graph-branch pair 0..255
    const int blk  = sub & 15;
    const int br   = gb >> 7;
    const int g    = gb & 127;
    const int wave = threadIdx.x >> 6;
    const int lane = threadIdx.x & 63;
    const int n0   = g * NPG + blk * 64 + wave * 16;

    const int*    rs = rowstart + br * NNODES;
    const int*    ct = cnt + br * NNODES;
    const float2* cs = csr + (size_t)br * NEDGES;
    const float*  dg = deg + br * NNODES;
    const float*  hh = h + (size_t)br * NNODES * 64;
    const float bias = (br ? bgb : bga)[lane];

    float psum = 0.f;
    for (int j = 0; j < 16; ++j) {
        int n = n0 + j;
        int r = __builtin_amdgcn_readfirstlane(rs[n]);
        int c = __builtin_amdgcn_readfirstlane(ct[n]);
        float a0 = 0.f, a1 = 0.f, a2 = 0.f, a3 = 0.f;
        int i = 0;
        for (; i + 4 <= c; i += 4) {
            float2 p0 = cs[r + i + 0];
            float2 p1 = cs[r + i + 1];
            float2 p2 = cs[r + i + 2];
            float2 p3 = cs[r + i + 3];
            a0 = fmaf(p0.y, hh[(size_t)__float_as_int(p0.x) * 64 + lane], a0);
            a1 = fmaf(p1.y, hh[(size_t)__float_as_int(p1.x) * 64 + lane], a1);
            a2 = fmaf(p2.y, hh[(size_t)__float_as_int(p2.x) * 64 + lane], a2);
            a3 = fmaf(p3.y, hh[(size_t)__float_as_int(p3.x) * 64 + lane], a3);
        }
        for (; i < c; ++i) {
            float2 p = cs[r + i];
            a0 = fmaf(p.y, hh[(size_t)__float_as_int(p.x) * 64 + lane], a0);
        }
        float d = dg[n] + 1.f;
        float v = (a0 + a1) + (a2 + a3) + hh[(size_t)n * 64 + lane] * (1.f / d) + bias;
        psum += fmaxf(v, 0.f);
    }
    red[threadIdx.x] = psum;
    __syncthreads();
    if (wave == 0) {
        float s = red[lane] + red[64 + lane] + red[128 + lane] + red[192 + lane];
        unsafeAtomicAdd(&pooled[br * (NB * 64) + g * 64 + lane], s);
    }
}

// ---------------- fallback scatter GCN (ws too small)
__global__ __launch_bounds__(256) void gcn_pool(
    const int* __restrict__ eia, const float* __restrict__ eaa,
    const int* __restrict__ eib, const float* __restrict__ eab,
    const float* __restrict__ deg, const float* __restrict__ h,
    const float* __restrict__ bga, const float* __restrict__ bgb,
    float* __restrict__ pooled) {
    __shared__ float acc[NPG * 16];   // 64 KB
    const int g  = blockIdx.x;
    const int q  = blockIdx.y;
    const int br = blockIdx.z;
    const int*   ei = br ? eib : eia;
    const float* ea = br ? eab : eaa;
    const float* dg = deg + br * NNODES;
    const float* hh = h + (size_t)br * NNODES * 64;
    const float* bg = br ? bgb : bga;
    const int tid = threadIdx.x;

    for (int i = tid; i < NPG * 16; i += 256) acc[i] = 0.f;
    __syncthreads();

    const int f16   = tid & 15;
    const int es    = tid >> 4;
    const int fof   = q * 16 + f16;
    const int gnode = g * NPG;
    const int ebase = g * EPG;

#pragma unroll 2
    for (int it = 0; it < EPG / 16; ++it) {
        int e   = ebase + it * 16 + es;
        int src = ei[e];
        int dst = ei[NEDGES + e];
        float w = ea[e];
        float nrm = rsqrtf(dg[src] + 1.f) * w * rsqrtf(dg[dst] + 1.f);
        float hv  = hh[(size_t)src * 64 + fof];
        unsafeAtomicAdd(&acc[(dst - gnode) * 16 + f16], nrm * hv);
    }
    __syncthreads();

    float psum = 0.f;
    float bias = bg[fof];
    for (int n = es; n < NPG; n += 16) {
        float d = dg[gnode + n] + 1.f;
        float v = acc[n * 16 + f16] + hh[(size_t)(gnode + n) * 64 + fof] * (1.f / d) + bias;
        psum += fmaxf(v, 0.f);
    }
    __syncthreads();
    acc[tid] = psum;
    __syncthreads();
    if (tid < 16) {
        float s = 0.f;
#pragma unroll
        for (int j = 0; j < 16; ++j) s += acc[j * 16 + tid];
        pooled[br * (NB * 64) + g * 64 + q * 16 + tid] = s;
    }
}

// ---------------- final MLP heads
__global__ __launch_bounds__(128) void final_mlp(
    const float* __restrict__ pooled, const float* __restrict__ linker,
    const float* __restrict__ W1, const float* __restrict__ b1,
    const float* __restrict__ W2, const float* __restrict__ b2,
    const float* __restrict__ W3, const float* __restrict__ b3,
    const float* __restrict__ Wcb, const float* __restrict__ bcb,
    const float* __restrict__ Wom, const float* __restrict__ bom,
    const float* __restrict__ Wth, const float* __restrict__ bth,
    const float* __restrict__ Wph, const float* __restrict__ bph,
    float* __restrict__ out) {
    __shared__ float inv[260];
    __shared__ float x1[128];
    __shared__ float x2[64];
    const int g = blockIdx.x;
    const int t = threadIdx.x;
    if (t < 64) {
        float pa = pooled[g * 64 + t];
        float pb = pooled[NB * 64 + g * 64 + t];
        inv[t]       = pa;
        inv[64 + t]  = pa * (1.f / 1024.f);
        inv[128 + t] = pb;
        inv[192 + t] = pb * (1.f / 1024.f);
    }
    if (t == 0) inv[256] = linker[g];
    __syncthreads();

    {
        float a = b1[t];
        for (int i = 0; i < 257; ++i) a = fmaf(inv[i], W1[i * 128 + t], a);
        x1[t] = fmaxf(a, 0.f);
    }
    __syncthreads();
    if (t < 64) {
        float a = b2[t];
        for (int i = 0; i < 128; ++i) a = fmaf(x1[i], W2[i * 64 + t], a);
        x2[t] = fmaxf(a, 0.f);
    }
    __syncthreads();
    if (t < 8) {
        if (t == 0) {
            float a = b3[0];
            for (int i = 0; i < 64; ++i) a = fmaf(x2[i], W3[i], a);
            out[g] = a;
        } else if (t == 1) {
            float a = bcb[0];
            for (int i = 0; i < 64; ++i) a = fmaf(x2[i], Wcb[i], a);
            out[128 + g] = a;
        } else if (t < 4) {
            int j = t - 2; float a = bom[j];
            for (int i = 0; i < 64; ++i) a = fmaf(x2[i], Wom[i * 2 + j], a);
            out[256 + g * 2 + j] = a;
        } else if (t < 6) {
            int j = t - 4; float a = bth[j];
            for (int i = 0; i < 64; ++i) a = fmaf(x2[i], Wth[i * 2 + j], a);
            out[512 + g * 2 + j] = a;
        } else {
            int j = t - 6; float a = bph[j];
            for (int i = 0; i < 64; ++i) a = fmaf(x2[i], Wph[i * 2 + j], a);
            out[768 + g * 2 + j] = a;
        }
    }
}

extern "C" void kernel_launch(void* const* d_in, const int* in_sizes, int n_in,
                              void* d_out, int out_size, void* d_ws, size_t ws_size,
                              hipStream_t stream) {
    const float* x_a  = (const float*)d_in[0];
    const int*   ei_a = (const int*)d_in[1];
    const float* ea_a = (const float*)d_in[2];
    const float* x_b  = (const float*)d_in[4];
    const int*   ei_b = (const int*)d_in[5];
    const float* ea_b = (const float*)d_in[6];
    const float* linker = (const float*)d_in[8];
    const float* W_pre1_a = (const float*)d_in[9];
    const float* b_pre1_a = (const float*)d_in[10];
    const float* W_pre2_a = (const float*)d_in[11];
    const float* b_pre2_a = (const float*)d_in[12];
    const float* W_gcn_a  = (const float*)d_in[13];
    const float* b_gcn_a  = (const float*)d_in[14];
    const float* W_pre1_b = (const float*)d_in[15];
    const float* b_pre1_b = (const float*)d_in[16];
    const float* W_pre2_b = (const float*)d_in[17];
    const float* b_pre2_b = (const float*)d_in[18];
    const float* W_gcn_b  = (const float*)d_in[19];
    const float* b_gcn_b  = (const float*)d_in[20];
    const float* W_lin1 = (const float*)d_in[21];
    const float* b_lin1 = (const float*)d_in[22];
    const float* W_lin2 = (const float*)d_in[23];
    const float* b_lin2 = (const float*)d_in[24];
    const float* W_lin3 = (const float*)d_in[25];
    const float* b_lin3 = (const float*)d_in[26];
    const float* W_cb = (const float*)d_in[27];
    const float* b_cb = (const float*)d_in[28];
    const float* W_om = (const float*)d_in[29];
    const float* b_om = (const float*)d_in[30];
    const float* W_th = (const float*)d_in[31];
    const float* b_th = (const float*)d_in[32];
    const float* W_ph = (const float*)d_in[33];
    const float* b_ph = (const float*)d_in[34];

    float* ws     = (float*)d_ws;
    float* deg    = ws + OFF_DEG;
    float* pooled = ws + OFF_POOLED;
    float* wtw    = ws + OFF_WT;
    float* h      = ws + OFF_H;
    int*   cnt      = (int*)(ws + OFF_CNT);
    int*   rowstart = (int*)(ws + OFF_ROWSTART);
    int*   cursor   = (int*)(ws + OFF_CURSOR);
    float2* csr     = (float2*)(ws + OFF_CSR);

    if (ws_size >= WS_NEEDED) {
        // CSR-gather + MFMA path
        hipMemsetAsync(deg, 0, (2 * NNODES + 2 * NB * 64) * sizeof(float), stream); // deg + pooled
        hipMemsetAsync(cnt, 0, 2 * NNODES * sizeof(int), stream);
        wprep<<<6, 256, 0, stream>>>(W_pre1_a, W_pre2_a, W_gcn_a,
                                     W_pre1_b, W_pre2_b, W_gcn_b,
                                     (unsigned short*)wtw);
        deg_cnt_kernel<<<2 * NEDGES / 256, 256, 0, stream>>>(ei_a, ea_a, ei_b, ea_b, deg, cnt);
        scan_kernel<<<256, 256, 0, stream>>>(cnt, rowstart, cursor);
        fill_kernel<<<2 * NEDGES / 256, 256, 0, stream>>>(ei_a, ea_a, ei_b, ea_b,
                                                          deg, cursor, csr);
        node_mlp_mfma<<<dim3(NNODES / 64, 2), 256, 0, stream>>>(
            x_a, x_b, (const unsigned short*)wtw,
            b_pre1_a, b_pre2_a, b_pre1_b, b_pre2_b, h);
        gcn_gather_pool<<<4096, 256, 0, stream>>>(rowstart, cnt, csr, deg, h,
                                                  b_gcn_a, b_gcn_b, pooled);
    } else {
        // fallback: scatter path, scalar MLP
        hipMemsetAsync(deg, 0, 2 * NNODES * sizeof(float), stream);
        wt_transpose<<<6, 256, 0, stream>>>(W_pre1_a, W_pre2_a, W_gcn_a,
                                            W_pre1_b, W_pre2_b, W_gcn_b, wtw);
        deg_kernel<<<2 * NEDGES / 256, 256, 0, stream>>>(ei_a, ea_a, ei_b, ea_b, deg);
        node_mlp<<<dim3(NNODES / 128, 2), 128, 0, stream>>>(x_a, x_b, wtw,
                                                            b_pre1_a, b_pre2_a,
                                                            b_pre1_b, b_pre2_b, h);
        gcn_pool<<<dim3(NB, 4, 2), 256, 0, stream>>>(ei_a, ea_a, ei_b, ea_b,
                                                     deg, h, b_gcn_a, b_gcn_b, pooled);
    }

    final_mlp<<<NB, 128, 0, stream>>>(pooled, linker,
                                      W_lin1, b_lin1, W_lin2, b_lin2, W_lin3, b_lin3,
                                      W_cb, b_cb, W_om, b_om, W_th, b_th, W_ph, b_ph,
                                      (float*)d_out);
}

// Round 6
// 471.321 us; speedup vs baseline: 4.5747x; 1.5753x over previous
//
#include <hip/hip_runtime.h>
#include <hip/hip_bf16.h>

#define NNODES 131072
#define NEDGES 2097152
#define NB     128
#define NPG    1024   // nodes per graph
#define EPG    16384  // edges per graph

// ws layout in 4-byte units. Prefix (deg..h) matches the fallback path's needs.
#define OFF_DEG      0                                   // 2*NNODES floats
#define OFF_POOLED   (OFF_DEG + 2*NNODES)                // 2*NB*64
#define OFF_WT       (OFF_POOLED + 2*NB*64)              // 96 KB: wfrag (main) / wt (fallback)
#define OFF_H        (OFF_WT + 6*4096)                   // 2*NNODES*64
#define OFF_CNT      (OFF_H + (size_t)2*NNODES*64)       // 2*NNODES ints
#define OFF_ROWSTART (OFF_CNT + 2*NNODES)                // 2*NNODES ints
#define OFF_CURSOR   (OFF_ROWSTART + 2*NNODES)           // 2*NNODES ints (unused, kept for layout)
#define OFF_CSR      (OFF_CURSOR + 2*NNODES)             // 2*NEDGES float2
#define WS_NEEDED    ((OFF_CSR + (size_t)4*NEDGES) * 4)

typedef __attribute__((ext_vector_type(8))) short bfrag;
typedef __attribute__((ext_vector_type(4))) float f32x4;

__device__ __forceinline__ unsigned short f2bf(float v) {
    unsigned int u = __float_as_uint(v);
    unsigned int r = (u + 0x7fffu + ((u >> 16) & 1u)) >> 16;
    return (unsigned short)r;
}
__device__ __forceinline__ float bf2f(unsigned short s) {
    return __uint_as_float(((unsigned int)s) << 16);
}

// ---------------- pack six 64x64 weights into split-bf16 MFMA B-fragments.
// k-convention must equal the A-side assembly (contiguous-8):
//   col f = ft*16 + (lane&15);   k = kt*32 + (lane>>4)*8 + i
__global__ void wprep(const float* __restrict__ w0, const float* __restrict__ w1,
                      const float* __restrict__ w2, const float* __restrict__ w3,
                      const float* __restrict__ w4, const float* __restrict__ w5,
                      unsigned short* __restrict__ wf) {
    int m = blockIdx.x;
    const float* w = (m == 0) ? w0 : (m == 1) ? w1 : (m == 2) ? w2
                   : (m == 3) ? w3 : (m == 4) ? w4 : w5;
    for (int idx = threadIdx.x; idx < 4096; idx += blockDim.x) {
        int ft   = idx >> 10;
        int kt   = (idx >> 9) & 1;
        int lane = (idx >> 3) & 63;
        int i    = idx & 7;
        int f = ft * 16 + (lane & 15);
        int k = kt * 32 + ((lane >> 4) << 3) + i;
        float v = w[k * 64 + f];
        unsigned short hi = f2bf(v);
        unsigned short lo = f2bf(v - bf2f(hi));
        wf[m * 8192 + idx]        = hi;
        wf[m * 8192 + 4096 + idx] = lo;
    }
}

// ---------------- fused CSR build: deg + cnt + scan + fill, all atomics in LDS.
// block = (graph g, branch br); exploits block-structured edges:
// src,dst of graph g are in [g*NPG,(g+1)*NPG), edges in [g*EPG,(g+1)*EPG).
__global__ __launch_bounds__(256) void csr_build(
    const int* __restrict__ eia, const float* __restrict__ eaa,
    const int* __restrict__ eib, const float* __restrict__ eab,
    float* __restrict__ deg, int* __restrict__ rowstart,
    int* __restrict__ cnt, float2* __restrict__ csr) {
    __shared__ float sdeg[NPG];   // pass1: weighted degree; then dinv
    __shared__ int   scnt[NPG];
    __shared__ int   scur[NPG];
    __shared__ int   sm[256];
    const int g  = blockIdx.x;
    const int br = blockIdx.y;
    const int* ei   = br ? eib : eia;
    const float* ea = br ? eab : eaa;
    const int t     = threadIdx.x;
    const int ebase = g * EPG;
    const int nbase = g * NPG;

    for (int i = t; i < NPG; i += 256) { sdeg[i] = 0.f; scnt[i] = 0; }
    __syncthreads();

    // pass 1: degree + in-degree count (LDS atomics)
#pragma unroll 4
    for (int it = 0; it < EPG / 256; ++it) {
        int e = ebase + it * 256 + t;
        int d = ei[NEDGES + e] - nbase;
        float w = ea[e];
        atomicAdd(&scnt[d], 1);
        atomicAdd(&sdeg[d], w);
    }
    __syncthreads();

    // write raw deg to global; replace sdeg with dinv = rsqrt(deg+1)
    for (int i = t; i < NPG; i += 256) {
        float dv = sdeg[i];
        deg[br * NNODES + nbase + i] = dv;
        sdeg[i] = rsqrtf(dv + 1.f);
    }

    // block scan of scnt (4 per thread) -> rowstart/cursor
    int c0 = scnt[t * 4 + 0], c1 = scnt[t * 4 + 1], c2 = scnt[t * 4 + 2], c3 = scnt[t * 4 + 3];
    int T = c0 + c1 + c2 + c3;
    sm[t] = T;
    __syncthreads();
    for (int off = 1; off < 256; off <<= 1) {
        int v = (t >= off) ? sm[t - off] : 0;
        __syncthreads();
        sm[t] += v;
        __syncthreads();
    }
    int excl = sm[t] - T;
    int base = ebase + excl;
    int r0 = base, r1 = base + c0, r2 = r1 + c1, r3 = r2 + c2;
    int nout = br * NNODES + nbase + t * 4;
    rowstart[nout + 0] = r0; rowstart[nout + 1] = r1;
    rowstart[nout + 2] = r2; rowstart[nout + 3] = r3;
    cnt[nout + 0] = c0; cnt[nout + 1] = c1; cnt[nout + 2] = c2; cnt[nout + 3] = c3;
    scur[t * 4 + 0] = r0; scur[t * 4 + 1] = r1;
    scur[t * 4 + 2] = r2; scur[t * 4 + 3] = r3;
    __syncthreads();

    // pass 2: fill CSR via LDS cursor atomics
    float2* cso = csr + (size_t)br * NEDGES;
#pragma unroll 4
    for (int it = 0; it < EPG / 256; ++it) {
        int e = ebase + it * 256 + t;
        int srcg = ei[e];
        int s = srcg - nbase;
        int d = ei[NEDGES + e] - nbase;
        float w = ea[e];
        int pos = atomicAdd(&scur[d], 1);
        float2 pr;
        pr.x = __int_as_float(srcg);
        pr.y = sdeg[s] * w * sdeg[d];
        cso[pos] = pr;
    }
}

// ---------------- MFMA node MLP: h = relu(relu(x@W1+b1)@W2+b2)@Wg
// Split-bf16 (hi/lo): x*W ~= xh*Wh + xl*Wh + xh*Wl (error ~2^-18 rel).
// wave = 16 nodes; per layer 4 ft * 2 kt * 3 terms = 24 mfma 16x16x32.
// A-side k-convention: k = kt*32 + (lane>>4)*8 + i  (contiguous-8; == wprep).
__global__ __launch_bounds__(256) void node_mlp_mfma(
    const float* __restrict__ xa, const float* __restrict__ xb,
    const unsigned short* __restrict__ wf,
    const float* __restrict__ b1a, const float* __restrict__ b2a,
    const float* __restrict__ b1b, const float* __restrict__ b2b,
    float* __restrict__ hout) {
    __shared__ float lds[4 * 16 * 65];
    const int br = blockIdx.y;
    const float* x = br ? xb : xa;
    const unsigned short* wfb = wf + br * 3 * 8192;
    const float* b1 = br ? b1b : b1a;
    const float* b2 = br ? b2b : b2a;
    const int wave = threadIdx.x >> 6;
    const int lane = threadIdx.x & 63;
    const int row  = lane & 15;
    const int kg   = lane >> 4;
    const int n0   = blockIdx.x * 64 + wave * 16;
    float* wlds = &lds[wave * 16 * 65];

    bfrag ahi[2], alo[2];
#pragma unroll
    for (int kt = 0; kt < 2; ++kt) {
        const float4* p = reinterpret_cast<const float4*>(
            x + (size_t)(n0 + row) * 64 + kt * 32 + kg * 8);
        float4 v0 = p[0], v1 = p[1];
        float vv[8] = {v0.x, v0.y, v0.z, v0.w, v1.x, v1.y, v1.z, v1.w};
        bfrag h, l;
#pragma unroll
        for (int i = 0; i < 8; ++i) {
            unsigned short hb = f2bf(vv[i]);
            unsigned short lb = f2bf(vv[i] - bf2f(hb));
            h[i] = (short)hb;
            l[i] = (short)lb;
        }
        ahi[kt] = h; alo[kt] = l;
    }

#pragma unroll
    for (int layer = 0; layer < 3; ++layer) {
        const unsigned short* wl = wfb + layer * 8192;
        bfrag bhi[4][2], blo[4][2];
#pragma unroll
        for (int ft = 0; ft < 4; ++ft)
#pragma unroll
            for (int kt = 0; kt < 2; ++kt) {
                bhi[ft][kt] = *reinterpret_cast<const bfrag*>(wl + ft * 1024 + kt * 512 + lane * 8);
                blo[ft][kt] = *reinterpret_cast<const bfrag*>(wl + 4096 + ft * 1024 + kt * 512 + lane * 8);
            }
        f32x4 acc[4];
#pragma unroll
        for (int ft = 0; ft < 4; ++ft) {
            float bv = (layer == 0) ? b1[ft * 16 + row]
                     : (layer == 1) ? b2[ft * 16 + row] : 0.f;
            acc[ft] = (f32x4){bv, bv, bv, bv};
        }
#pragma unroll
        for (int ft = 0; ft < 4; ++ft)
#pragma unroll
            for (int kt = 0; kt < 2; ++kt) {
                acc[ft] = __builtin_amdgcn_mfma_f32_16x16x32_bf16(ahi[kt], bhi[ft][kt], acc[ft], 0, 0, 0);
                acc[ft] = __builtin_amdgcn_mfma_f32_16x16x32_bf16(alo[kt], bhi[ft][kt], acc[ft], 0, 0, 0);
                acc[ft] = __builtin_amdgcn_mfma_f32_16x16x32_bf16(ahi[kt], blo[ft][kt], acc[ft], 0, 0, 0);
            }

        if (layer < 2) {
#pragma unroll
            for (int ft = 0; ft < 4; ++ft)
#pragma unroll
                for (int r = 0; r < 4; ++r)
                    wlds[(kg * 4 + r) * 65 + ft * 16 + row] = fmaxf(acc[ft][r], 0.f);
            __syncthreads();
#pragma unroll
            for (int kt = 0; kt < 2; ++kt) {
                const float* rp = &wlds[row * 65 + kt * 32 + kg * 8];
                bfrag h, l;
#pragma unroll
                for (int i = 0; i < 8; ++i) {
                    float v = rp[i];
                    unsigned short hb = f2bf(v);
                    unsigned short lb = f2bf(v - bf2f(hb));
                    h[i] = (short)hb;
                    l[i] = (short)lb;
                }
                ahi[kt] = h; alo[kt] = l;
            }
            __syncthreads();
        } else {
            float* hp = hout + (size_t)br * NNODES * 64 + (size_t)n0 * 64;
#pragma unroll
            for (int ft = 0; ft < 4; ++ft)
#pragma unroll
                for (int r = 0; r < 4; ++r)
                    hp[(kg * 4 + r) * 64 + ft * 16 + row] = acc[ft][r];
        }
    }
}

// ---------------- fallback kernels (ws too small): scalar path
__global__ void wt_transpose(const float* __restrict__ w0, const float* __restrict__ w1,
                             const float* __restrict__ w2, const float* __restrict__ w3,
                             const float* __restrict__ w4, const float* __restrict__ w5,
                             float* __restrict__ wt) {
    int m = blockIdx.x;
    const float* w = (m == 0) ? w0 : (m == 1) ? w1 : (m == 2) ? w2
                   : (m == 3) ? w3 : (m == 4) ? w4 : w5;
    for (int idx = threadIdx.x; idx < 4096; idx += blockDim.x) {
        int f = idx >> 6, k = idx & 63;
        wt[m * 4096 + idx] = w[k * 64 + f];
    }
}

__global__ __launch_bounds__(256) void deg_kernel(
    const int* __restrict__ eia, const float* __restrict__ eaa,
    const int* __restrict__ eib, const float* __restrict__ eab,
    float* __restrict__ deg) {
    int i = blockIdx.x * 256 + threadIdx.x;
    int br = (i >= NEDGES) ? 1 : 0;
    int e  = i - br * NEDGES;
    const int*   ei = br ? eib : eia;
    const float* ea = br ? eab : eaa;
    int dst = ei[NEDGES + e];
    unsafeAtomicAdd(&deg[br * NNODES + dst], ea[e]);
}

__global__ __launch_bounds__(128) void node_mlp(
    const float* __restrict__ xa, const float* __restrict__ xb,
    const float* __restrict__ wt,
    const float* __restrict__ b1a, const float* __restrict__ b2a,
    const float* __restrict__ b1b, const float* __restrict__ b2b,
    float* __restrict__ hout) {
    __shared__ float bounce[128 * 65];
    const int br = blockIdx.y;
    const float* x   = br ? xb : xa;
    const float* wt1 = wt + br * 3 * 4096;
    const float* wt2 = wt1 + 4096;
    const float* wt3 = wt2 + 4096;
    const float* b1  = br ? b1b : b1a;
    const float* b2  = br ? b2b : b2a;
    const int node = blockIdx.x * 128 + threadIdx.x;

    float xr[64];
    const float4* xp = reinterpret_cast<const float4*>(x + (size_t)node * 64);
#pragma unroll
    for (int i = 0; i < 16; ++i) {
        float4 v = xp[i];
        xr[4 * i + 0] = v.x; xr[4 * i + 1] = v.y; xr[4 * i + 2] = v.z; xr[4 * i + 3] = v.w;
    }
    float* myrow = &bounce[threadIdx.x * 65];

    for (int f = 0; f < 64; ++f) {
        const float* w = wt1 + f * 64;
        float acc = b1[f];
#pragma unroll
        for (int k = 0; k < 64; ++k) acc = fmaf(xr[k], w[k], acc);
        myrow[f] = fmaxf(acc, 0.f);
    }
#pragma unroll
    for (int k = 0; k < 64; ++k) xr[k] = myrow[k];

    for (int f = 0; f < 64; ++f) {
        const float* w = wt2 + f * 64;
        float acc = b2[f];
#pragma unroll
        for (int k = 0; k < 64; ++k) acc = fmaf(xr[k], w[k], acc);
        myrow[f] = fmaxf(acc, 0.f);
    }
#pragma unroll
    for (int k = 0; k < 64; ++k) xr[k] = myrow[k];

    float* hp = hout + (size_t)br * NNODES * 64 + (size_t)node * 64;
    for (int f = 0; f < 64; ++f) {
        const float* w = wt3 + f * 64;
        float acc = 0.f;
#pragma unroll
        for (int k = 0; k < 64; ++k) acc = fmaf(xr[k], w[k], acc);
        hp[f] = acc;
    }
}

// ---------------- CSR gather GCN + self loop + bias + relu + graph-sum pool
__global__ __launch_bounds__(256) void gcn_gather_pool(
    const int* __restrict__ rowstart, const int* __restrict__ cnt,
    const float2* __restrict__ csr, const float* __restrict__ deg,
    const float* __restrict__ h,
    const float* __restrict__ bga, const float* __restrict__ bgb,
    float* __restrict__ pooled) {
    __shared__ float red[256];
    const int bid  = blockIdx.x;
    const int xcd  = bid & 7;
    const int sub  = bid >> 3;                  // 0..511
    const int gb   = xcd * 32 + (sub >> 4);     // graph-branch pair 0..255
    const int blk  = sub & 15;
    const int br   = gb >> 7;
    const int g    = gb & 127;
    const int wave = threadIdx.x >> 6;
    const int lane = threadIdx.x & 63;
    const int n0   = g * NPG + blk * 64 + wave * 16;

    const int*    rs = rowstart + br * NNODES;
    const int*    ct = cnt + br * NNODES;
    const float2* cs = csr + (size_t)br * NEDGES;
    const float*  dg = deg + br * NNODES;
    const float*  hh = h + (size_t)br * NNODES * 64;
    const float bias = (br ? bgb : bga)[lane];

    float psum = 0.f;
    for (int j = 0; j < 16; ++j) {
        int n = n0 + j;
        int r = __builtin_amdgcn_readfirstlane(rs[n]);
        int c = __builtin_amdgcn_readfirstlane(ct[n]);
        float a0 = 0.f, a1 = 0.f, a2 = 0.f, a3 = 0.f;
        int i = 0;
        for (; i + 4 <= c; i += 4) {
            float2 p0 = cs[r + i + 0];
            float2 p1 = cs[r + i + 1];
            float2 p2 = cs[r + i + 2];
            float2 p3 = cs[r + i + 3];
            a0 = fmaf(p0.y, hh[(size_t)__float_as_int(p0.x) * 64 + lane], a0);
            a1 = fmaf(p1.y, hh[(size_t)__float_as_int(p1.x) * 64 + lane], a1);
            a2 = fmaf(p2.y, hh[(size_t)__float_as_int(p2.x) * 64 + lane], a2);
            a3 = fmaf(p3.y, hh[(size_t)__float_as_int(p3.x) * 64 + lane], a3);
        }
        for (; i < c; ++i) {
            float2 p = cs[r + i];
            a0 = fmaf(p.y, hh[(size_t)__float_as_int(p.x) * 64 + lane], a0);
        }
        float d = dg[n] + 1.f;
        float v = (a0 + a1) + (a2 + a3) + hh[(size_t)n * 64 + lane] * (1.f / d) + bias;
        psum += fmaxf(v, 0.f);
    }
    red[threadIdx.x] = psum;
    __syncthreads();
    if (wave == 0) {
        float s = red[lane] + red[64 + lane] + red[128 + lane] + red[192 + lane];
        unsafeAtomicAdd(&pooled[br * (NB * 64) + g * 64 + lane], s);
    }
}

// ---------------- fallback scatter GCN (ws too small)
__global__ __launch_bounds__(256) void gcn_pool(
    const int* __restrict__ eia, const float* __restrict__ eaa,
    const int* __restrict__ eib, const float* __restrict__ eab,
    const float* __restrict__ deg, const float* __restrict__ h,
    const float* __restrict__ bga, const float* __restrict__ bgb,
    float* __restrict__ pooled) {
    __shared__ float acc[NPG * 16];   // 64 KB
    const int g  = blockIdx.x;
    const int q  = blockIdx.y;
    const int br = blockIdx.z;
    const int*   ei = br ? eib : eia;
    const float* ea = br ? eab : eaa;
    const float* dg = deg + br * NNODES;
    const float* hh = h + (size_t)br * NNODES * 64;
    const float* bg = br ? bgb : bga;
    const int tid = threadIdx.x;

    for (int i = tid; i < NPG * 16; i += 256) acc[i] = 0.f;
    __syncthreads();

    const int f16   = tid & 15;
    const int es    = tid >> 4;
    const int fof   = q * 16 + f16;
    const int gnode = g * NPG;
    const int ebase = g * EPG;

#pragma unroll 2
    for (int it = 0; it < EPG / 16; ++it) {
        int e   = ebase + it * 16 + es;
        int src = ei[e];
        int dst = ei[NEDGES + e];
        float w = ea[e];
        float nrm = rsqrtf(dg[src] + 1.f) * w * rsqrtf(dg[dst] + 1.f);
        float hv  = hh[(size_t)src * 64 + fof];
        unsafeAtomicAdd(&acc[(dst - gnode) * 16 + f16], nrm * hv);
    }
    __syncthreads();

    float psum = 0.f;
    float bias = bg[fof];
    for (int n = es; n < NPG; n += 16) {
        float d = dg[gnode + n] + 1.f;
        float v = acc[n * 16 + f16] + hh[(size_t)(gnode + n) * 64 + fof] * (1.f / d) + bias;
        psum += fmaxf(v, 0.f);
    }
    __syncthreads();
    acc[tid] = psum;
    __syncthreads();
    if (tid < 16) {
        float s = 0.f;
#pragma unroll
        for (int j = 0; j < 16; ++j) s += acc[j * 16 + tid];
        pooled[br * (NB * 64) + g * 64 + q * 16 + tid] = s;
    }
}

// ---------------- final MLP heads
__global__ __launch_bounds__(128) void final_mlp(
    const float* __restrict__ pooled, const float* __restrict__ linker,
    const float* __restrict__ W1, const float* __restrict__ b1,
    const float* __restrict__ W2, const float* __restrict__ b2,
    const float* __restrict__ W3, const float* __restrict__ b3,
    const float* __restrict__ Wcb, const float* __restrict__ bcb,
    const float* __restrict__ Wom, const float* __restrict__ bom,
    const float* __restrict__ Wth, const float* __restrict__ bth,
    const float* __restrict__ Wph, const float* __restrict__ bph,
    float* __restrict__ out) {
    __shared__ float inv[260];
    __shared__ float x1[128];
    __shared__ float x2[64];
    const int g = blockIdx.x;
    const int t = threadIdx.x;
    if (t < 64) {
        float pa = pooled[g * 64 + t];
        float pb = pooled[NB * 64 + g * 64 + t];
        inv[t]       = pa;
        inv[64 + t]  = pa * (1.f / 1024.f);
        inv[128 + t] = pb;
        inv[192 + t] = pb * (1.f / 1024.f);
    }
    if (t == 0) inv[256] = linker[g];
    __syncthreads();

    {
        float a = b1[t];
        for (int i = 0; i < 257; ++i) a = fmaf(inv[i], W1[i * 128 + t], a);
        x1[t] = fmaxf(a, 0.f);
    }
    __syncthreads();
    if (t < 64) {
        float a = b2[t];
        for (int i = 0; i < 128; ++i) a = fmaf(x1[i], W2[i * 64 + t], a);
        x2[t] = fmaxf(a, 0.f);
    }
    __syncthreads();
    if (t < 8) {
        if (t == 0) {
            float a = b3[0];
            for (int i = 0; i < 64; ++i) a = fmaf(x2[i], W3[i], a);
            out[g] = a;
        } else if (t == 1) {
            float a = bcb[0];
            for (int i = 0; i < 64; ++i) a = fmaf(x2[i], Wcb[i], a);
            out[128 + g] = a;
        } else if (t < 4) {
            int j = t - 2; float a = bom[j];
            for (int i = 0; i < 64; ++i) a = fmaf(x2[i], Wom[i * 2 + j], a);
            out[256 + g * 2 + j] = a;
        } else if (t < 6) {
            int j = t - 4; float a = bth[j];
            for (int i = 0; i < 64; ++i) a = fmaf(x2[i], Wth[i * 2 + j], a);
            out[512 + g * 2 + j] = a;
        } else {
            int j = t - 6; float a = bph[j];
            for (int i = 0; i < 64; ++i) a = fmaf(x2[i], Wph[i * 2 + j], a);
            out[768 + g * 2 + j] = a;
        }
    }
}

extern "C" void kernel_launch(void* const* d_in, const int* in_sizes, int n_in,
                              void* d_out, int out_size, void* d_ws, size_t ws_size,
                              hipStream_t stream) {
    const float* x_a  = (const float*)d_in[0];
    const int*   ei_a = (const int*)d_in[1];
    const float* ea_a = (const float*)d_in[2];
    const float* x_b  = (const float*)d_in[4];
    const int*   ei_b = (const int*)d_in[5];
    const float* ea_b = (const float*)d_in[6];
    const float* linker = (const float*)d_in[8];
    const float* W_pre1_a = (const float*)d_in[9];
    const float* b_pre1_a = (const float*)d_in[10];
    const float* W_pre2_a = (const float*)d_in[11];
    const float* b_pre2_a = (const float*)d_in[12];
    const float* W_gcn_a  = (const float*)d_in[13];
    const float* b_gcn_a  = (const float*)d_in[14];
    const float* W_pre1_b = (const float*)d_in[15];
    const float* b_pre1_b = (const float*)d_in[16];
    const float* W_pre2_b = (const float*)d_in[17];
    const float* b_pre2_b = (const float*)d_in[18];
    const float* W_gcn_b  = (const float*)d_in[19];
    const float* b_gcn_b  = (const float*)d_in[20];
    const float* W_lin1 = (const float*)d_in[21];
    const float* b_lin1 = (const float*)d_in[22];
    const float* W_lin2 = (const float*)d_in[23];
    const float* b_lin2 = (const float*)d_in[24];
    const float* W_lin3 = (const float*)d_in[25];
    const float* b_lin3 = (const float*)d_in[26];
    const float* W_cb = (const float*)d_in[27];
    const float* b_cb = (const float*)d_in[28];
    const float* W_om = (const float*)d_in[29];
    const float* b_om = (const float*)d_in[30];
    const float* W_th = (const float*)d_in[31];
    const float* b_th = (const float*)d_in[32];
    const float* W_ph = (const float*)d_in[33];
    const float* b_ph = (const float*)d_in[34];

    float* ws     = (float*)d_ws;
    float* deg    = ws + OFF_DEG;
    float* pooled = ws + OFF_POOLED;
    float* wtw    = ws + OFF_WT;
    float* h      = ws + OFF_H;
    int*   cnt      = (int*)(ws + OFF_CNT);
    int*   rowstart = (int*)(ws + OFF_ROWSTART);
    float2* csr     = (float2*)(ws + OFF_CSR);

    if (ws_size >= WS_NEEDED) {
        // main path: fused LDS CSR build + MFMA MLP + CSR gather
        hipMemsetAsync(pooled, 0, 2 * NB * 64 * sizeof(float), stream);
        wprep<<<6, 256, 0, stream>>>(W_pre1_a, W_pre2_a, W_gcn_a,
                                     W_pre1_b, W_pre2_b, W_gcn_b,
                                     (unsigned short*)wtw);
        csr_build<<<dim3(NB, 2), 256, 0, stream>>>(ei_a, ea_a, ei_b, ea_b,
                                                   deg, rowstart, cnt, csr);
        node_mlp_mfma<<<dim3(NNODES / 64, 2), 256, 0, stream>>>(
            x_a, x_b, (const unsigned short*)wtw,
            b_pre1_a, b_pre2_a, b_pre1_b, b_pre2_b, h);
        gcn_gather_pool<<<4096, 256, 0, stream>>>(rowstart, cnt, csr, deg, h,
                                                  b_gcn_a, b_gcn_b, pooled);
    } else {
        // fallback: scatter path, scalar MLP
        hipMemsetAsync(deg, 0, 2 * NNODES * sizeof(float), stream);
        wt_transpose<<<6, 256, 0, stream>>>(W_pre1_a, W_pre2_a, W_gcn_a,
                                            W_pre1_b, W_pre2_b, W_gcn_b, wtw);
        deg_kernel<<<2 * NEDGES / 256, 256, 0, stream>>>(ei_a, ea_a, ei_b, ea_b, deg);
        node_mlp<<<dim3(NNODES / 128, 2), 128, 0, stream>>>(x_a, x_b, wtw,
                                                            b_pre1_a, b_pre2_a,
                                                            b_pre1_b, b_pre2_b, h);
        gcn_pool<<<dim3(NB, 4, 2), 256, 0, stream>>>(ei_a, ea_a, ei_b, ea_b,
                                                     deg, h, b_gcn_a, b_gcn_b, pooled);
    }

    final_mlp<<<NB, 128, 0, stream>>>(pooled, linker,
                                      W_lin1, b_lin1, W_lin2, b_lin2, W_lin3, b_lin3,
                                      W_cb, b_cb, W_om, b_om, W_th, b_th, W_ph, b_ph,
                                      (float*)d_out);
}

// Round 7
// 405.843 us; speedup vs baseline: 5.3128x; 1.1613x over previous
//
#include <hip/hip_runtime.h>
#include <hip/hip_bf16.h>

#define NNODES 131072
#define NEDGES 2097152
#define NB     128
#define NPG    1024   // nodes per graph
#define EPG    16384  // edges per graph

// ws layout in 4-byte units.
#define OFF_DEG      0                                   // 2*NNODES floats
#define OFF_POOLED   (OFF_DEG + 2*NNODES)                // 2*NB*64
#define OFF_WT       (OFF_POOLED + 2*NB*64)              // 96 KB: wfrag (main) / wt (fallback)
#define OFF_H        (OFF_WT + 6*4096)                   // 2*NNODES*64
#define OFF_CNT      (OFF_H + (size_t)2*NNODES*64)       // 2*NNODES ints
#define OFF_ROWSTART (OFF_CNT + 2*NNODES)                // 2*NNODES ints
#define OFF_CURSOR   (OFF_ROWSTART + 2*NNODES)           // 2*NNODES ints (layout keep)
#define OFF_CSR      (OFF_CURSOR + 2*NNODES)             // 2*NEDGES float2
#define WS_NEEDED    ((OFF_CSR + (size_t)4*NEDGES) * 4)

#define CSRB_LDS 145408   // 128K csr + 4K sdeg + 4K scnt + 4K scur + 2K scan

typedef __attribute__((ext_vector_type(8))) short bfrag;
typedef __attribute__((ext_vector_type(4))) float f32x4;

__device__ __forceinline__ unsigned short f2bf(float v) {
    unsigned int u = __float_as_uint(v);
    unsigned int r = (u + 0x7fffu + ((u >> 16) & 1u)) >> 16;
    return (unsigned short)r;
}
__device__ __forceinline__ float bf2f(unsigned short s) {
    return __uint_as_float(((unsigned int)s) << 16);
}

// ---------------- pack six 64x64 weights into split-bf16 MFMA B-fragments.
// k-convention must equal the A-side assembly (contiguous-8):
//   col f = ft*16 + (lane&15);   k = kt*32 + (lane>>4)*8 + i
__global__ void wprep(const float* __restrict__ w0, const float* __restrict__ w1,
                      const float* __restrict__ w2, const float* __restrict__ w3,
                      const float* __restrict__ w4, const float* __restrict__ w5,
                      unsigned short* __restrict__ wf) {
    int m = blockIdx.x;
    const float* w = (m == 0) ? w0 : (m == 1) ? w1 : (m == 2) ? w2
                   : (m == 3) ? w3 : (m == 4) ? w4 : w5;
    for (int idx = threadIdx.x; idx < 4096; idx += blockDim.x) {
        int ft   = idx >> 10;
        int kt   = (idx >> 9) & 1;
        int lane = (idx >> 3) & 63;
        int i    = idx & 7;
        int f = ft * 16 + (lane & 15);
        int k = kt * 32 + ((lane >> 4) << 3) + i;
        float v = w[k * 64 + f];
        unsigned short hi = f2bf(v);
        unsigned short lo = f2bf(v - bf2f(hi));
        wf[m * 8192 + idx]        = hi;
        wf[m * 8192 + 4096 + idx] = lo;
    }
}

// ---------------- CSR build v2: deg+cnt+scan+fill all in LDS, csr staged in
// LDS and written out COALESCED (float4). block=(g,br), 512 thr, 142 KB LDS.
__global__ __launch_bounds__(512) void csr_build2(
    const int* __restrict__ eia, const float* __restrict__ eaa,
    const int* __restrict__ eib, const float* __restrict__ eab,
    float* __restrict__ deg, int* __restrict__ rowstart,
    int* __restrict__ cnt, float2* __restrict__ csr) {
    extern __shared__ char smem[];
    float2* scsr = (float2*)smem;                    // 16384 * 8B = 128 KB
    float*  sdeg = (float*)(smem + 131072);          // 4 KB
    int*    scnt = (int*)(smem + 135168);            // 4 KB
    int*    scur = (int*)(smem + 139264);            // 4 KB
    int*    sm   = (int*)(smem + 143360);            // 2 KB
    const int g  = blockIdx.x;
    const int br = blockIdx.y;
    const int* ei   = br ? eib : eia;
    const float* ea = br ? eab : eaa;
    const int t     = threadIdx.x;
    const int ebase = g * EPG;
    const int nbase = g * NPG;

    for (int i = t; i < NPG; i += 512) { sdeg[i] = 0.f; scnt[i] = 0; }
    __syncthreads();

    // pass 1: weighted degree + in-degree count (LDS atomics)
#pragma unroll 4
    for (int it = 0; it < EPG / 512; ++it) {
        int e = ebase + it * 512 + t;
        int d = ei[NEDGES + e] - nbase;
        float w = ea[e];
        atomicAdd(&scnt[d], 1);
        atomicAdd(&sdeg[d], w);
    }
    __syncthreads();

    // write raw deg; replace sdeg with dinv = rsqrt(deg+1)
    for (int i = t; i < NPG; i += 512) {
        float dv = sdeg[i];
        deg[br * NNODES + nbase + i] = dv;
        sdeg[i] = rsqrtf(dv + 1.f);
    }

    // block scan of scnt (2 per thread) -> local rowstart/cursor
    int c0 = scnt[t * 2 + 0], c1 = scnt[t * 2 + 1];
    int T = c0 + c1;
    sm[t] = T;
    __syncthreads();
    for (int off = 1; off < 512; off <<= 1) {
        int v = (t >= off) ? sm[t - off] : 0;
        __syncthreads();
        sm[t] += v;
        __syncthreads();
    }
    int excl = sm[t] - T;
    int r0 = excl, r1 = excl + c0;                 // local positions 0..16383
    int nout = br * NNODES + nbase + t * 2;
    rowstart[nout + 0] = ebase + r0;
    rowstart[nout + 1] = ebase + r1;
    cnt[nout + 0] = c0; cnt[nout + 1] = c1;
    scur[t * 2 + 0] = r0; scur[t * 2 + 1] = r1;
    __syncthreads();

    // pass 2: fill LDS csr via LDS cursor atomics
#pragma unroll 4
    for (int it = 0; it < EPG / 512; ++it) {
        int e = ebase + it * 512 + t;
        int srcg = ei[e];
        int s = srcg - nbase;
        int d = ei[NEDGES + e] - nbase;
        float w = ea[e];
        int pos = atomicAdd(&scur[d], 1);
        float2 pr;
        pr.x = __int_as_float(srcg);
        pr.y = sdeg[s] * w * sdeg[d];
        scsr[pos] = pr;
    }
    __syncthreads();

    // coalesced copy-out: 16384 float2 = 8192 float4
    float4* dst4 = (float4*)(csr + (size_t)br * NEDGES + ebase);
    const float4* src4 = (const float4*)scsr;
    for (int i = t; i < 8192; i += 512) dst4[i] = src4[i];
}

// ---------------- fallback CSR build (round-6 version, static 13 KB LDS)
__global__ __launch_bounds__(256) void csr_build(
    const int* __restrict__ eia, const float* __restrict__ eaa,
    const int* __restrict__ eib, const float* __restrict__ eab,
    float* __restrict__ deg, int* __restrict__ rowstart,
    int* __restrict__ cnt, float2* __restrict__ csr) {
    __shared__ float sdeg[NPG];
    __shared__ int   scnt[NPG];
    __shared__ int   scur[NPG];
    __shared__ int   sm[256];
    const int g  = blockIdx.x;
    const int br = blockIdx.y;
    const int* ei   = br ? eib : eia;
    const float* ea = br ? eab : eaa;
    const int t     = threadIdx.x;
    const int ebase = g * EPG;
    const int nbase = g * NPG;

    for (int i = t; i < NPG; i += 256) { sdeg[i] = 0.f; scnt[i] = 0; }
    __syncthreads();
#pragma unroll 4
    for (int it = 0; it < EPG / 256; ++it) {
        int e = ebase + it * 256 + t;
        int d = ei[NEDGES + e] - nbase;
        float w = ea[e];
        atomicAdd(&scnt[d], 1);
        atomicAdd(&sdeg[d], w);
    }
    __syncthreads();
    for (int i = t; i < NPG; i += 256) {
        float dv = sdeg[i];
        deg[br * NNODES + nbase + i] = dv;
        sdeg[i] = rsqrtf(dv + 1.f);
    }
    int c0 = scnt[t * 4 + 0], c1 = scnt[t * 4 + 1], c2 = scnt[t * 4 + 2], c3 = scnt[t * 4 + 3];
    int T = c0 + c1 + c2 + c3;
    sm[t] = T;
    __syncthreads();
    for (int off = 1; off < 256; off <<= 1) {
        int v = (t >= off) ? sm[t - off] : 0;
        __syncthreads();
        sm[t] += v;
        __syncthreads();
    }
    int excl = sm[t] - T;
    int base = ebase + excl;
    int r0 = base, r1 = base + c0, r2 = r1 + c1, r3 = r2 + c2;
    int nout = br * NNODES + nbase + t * 4;
    rowstart[nout + 0] = r0; rowstart[nout + 1] = r1;
    rowstart[nout + 2] = r2; rowstart[nout + 3] = r3;
    cnt[nout + 0] = c0; cnt[nout + 1] = c1; cnt[nout + 2] = c2; cnt[nout + 3] = c3;
    scur[t * 4 + 0] = r0; scur[t * 4 + 1] = r1;
    scur[t * 4 + 2] = r2; scur[t * 4 + 3] = r3;
    __syncthreads();
    float2* cso = csr + (size_t)br * NEDGES;
#pragma unroll 4
    for (int it = 0; it < EPG / 256; ++it) {
        int e = ebase + it * 256 + t;
        int srcg = ei[e];
        int s = srcg - nbase;
        int d = ei[NEDGES + e] - nbase;
        float w = ea[e];
        int pos = atomicAdd(&scur[d], 1);
        float2 pr;
        pr.x = __int_as_float(srcg);
        pr.y = sdeg[s] * w * sdeg[d];
        cso[pos] = pr;
    }
}

// ---------------- MFMA node MLP: h = relu(relu(x@W1+b1)@W2+b2)@Wg
// Split-bf16 (hi/lo): x*W ~= xh*Wh + xl*Wh + xh*Wl (error ~2^-18 rel).
__global__ __launch_bounds__(256) void node_mlp_mfma(
    const float* __restrict__ xa, const float* __restrict__ xb,
    const unsigned short* __restrict__ wf,
    const float* __restrict__ b1a, const float* __restrict__ b2a,
    const float* __restrict__ b1b, const float* __restrict__ b2b,
    float* __restrict__ hout) {
    __shared__ float lds[4 * 16 * 65];
    const int br = blockIdx.y;
    const float* x = br ? xb : xa;
    const unsigned short* wfb = wf + br * 3 * 8192;
    const float* b1 = br ? b1b : b1a;
    const float* b2 = br ? b2b : b2a;
    const int wave = threadIdx.x >> 6;
    const int lane = threadIdx.x & 63;
    const int row  = lane & 15;
    const int kg   = lane >> 4;
    const int n0   = blockIdx.x * 64 + wave * 16;
    float* wlds = &lds[wave * 16 * 65];

    bfrag ahi[2], alo[2];
#pragma unroll
    for (int kt = 0; kt < 2; ++kt) {
        const float4* p = reinterpret_cast<const float4*>(
            x + (size_t)(n0 + row) * 64 + kt * 32 + kg * 8);
        float4 v0 = p[0], v1 = p[1];
        float vv[8] = {v0.x, v0.y, v0.z, v0.w, v1.x, v1.y, v1.z, v1.w};
        bfrag h, l;
#pragma unroll
        for (int i = 0; i < 8; ++i) {
            unsigned short hb = f2bf(vv[i]);
            unsigned short lb = f2bf(vv[i] - bf2f(hb));
            h[i] = (short)hb;
            l[i] = (short)lb;
        }
        ahi[kt] = h; alo[kt] = l;
    }

#pragma unroll
    for (int layer = 0; layer < 3; ++layer) {
        const unsigned short* wl = wfb + layer * 8192;
        bfrag bhi[4][2], blo[4][2];
#pragma unroll
        for (int ft = 0; ft < 4; ++ft)
#pragma unroll
            for (int kt = 0; kt < 2; ++kt) {
                bhi[ft][kt] = *reinterpret_cast<const bfrag*>(wl + ft * 1024 + kt * 512 + lane * 8);
                blo[ft][kt] = *reinterpret_cast<const bfrag*>(wl + 4096 + ft * 1024 + kt * 512 + lane * 8);
            }
        f32x4 acc[4];
#pragma unroll
        for (int ft = 0; ft < 4; ++ft) {
            float bv = (layer == 0) ? b1[ft * 16 + row]
                     : (layer == 1) ? b2[ft * 16 + row] : 0.f;
            acc[ft] = (f32x4){bv, bv, bv, bv};
        }
#pragma unroll
        for (int ft = 0; ft < 4; ++ft)
#pragma unroll
            for (int kt = 0; kt < 2; ++kt) {
                acc[ft] = __builtin_amdgcn_mfma_f32_16x16x32_bf16(ahi[kt], bhi[ft][kt], acc[ft], 0, 0, 0);
                acc[ft] = __builtin_amdgcn_mfma_f32_16x16x32_bf16(alo[kt], bhi[ft][kt], acc[ft], 0, 0, 0);
                acc[ft] = __builtin_amdgcn_mfma_f32_16x16x32_bf16(ahi[kt], blo[ft][kt], acc[ft], 0, 0, 0);
            }

        if (layer < 2) {
#pragma unroll
            for (int ft = 0; ft < 4; ++ft)
#pragma unroll
                for (int r = 0; r < 4; ++r)
                    wlds[(kg * 4 + r) * 65 + ft * 16 + row] = fmaxf(acc[ft][r], 0.f);
            __syncthreads();
#pragma unroll
            for (int kt = 0; kt < 2; ++kt) {
                const float* rp = &wlds[row * 65 + kt * 32 + kg * 8];
                bfrag h, l;
#pragma unroll
                for (int i = 0; i < 8; ++i) {
                    float v = rp[i];
                    unsigned short hb = f2bf(v);
                    unsigned short lb = f2bf(v - bf2f(hb));
                    h[i] = (short)hb;
                    l[i] = (short)lb;
                }
                ahi[kt] = h; alo[kt] = l;
            }
            __syncthreads();
        } else {
            float* hp = hout + (size_t)br * NNODES * 64 + (size_t)n0 * 64;
#pragma unroll
            for (int ft = 0; ft < 4; ++ft)
#pragma unroll
                for (int r = 0; r < 4; ++r)
                    hp[(kg * 4 + r) * 64 + ft * 16 + row] = acc[ft][r];
        }
    }
}

// ---------------- CSR gather GCN + self loop + bias + relu + graph-sum pool
__global__ __launch_bounds__(256) void gcn_gather_pool(
    const int* __restrict__ rowstart, const int* __restrict__ cnt,
    const float2* __restrict__ csr, const float* __restrict__ deg,
    const float* __restrict__ h,
    const float* __restrict__ bga, const float* __restrict__ bgb,
    float* __restrict__ pooled) {
    __shared__ float red[256];
    const int bid  = blockIdx.x;
    const int xcd  = bid & 7;
    const int sub  = bid >> 3;                  // 0..511
    const int gb   = xcd * 32 + (sub >> 4);     // graph-branch pair 0..255
    const int blk  = sub & 15;
    const int br   = gb >> 7;
    const int g    = gb & 127;
    const int wave = threadIdx.x >> 6;
    const int lane = threadIdx.x & 63;
    const int n0   = g * NPG + blk * 64 + wave * 16;

    const int*    rs = rowstart + br * NNODES;
    const int*    ct = cnt + br * NNODES;
    const float2* cs = csr + (size_t)br * NEDGES;
    const float*  dg = deg + br * NNODES;
    const float*  hh = h + (size_t)br * NNODES * 64;
    const float bias = (br ? bgb : bga)[lane];

    float psum = 0.f;
    for (int j = 0; j < 16; ++j) {
        int n = n0 + j;
        int r = __builtin_amdgcn_readfirstlane(rs[n]);
        int c = __builtin_amdgcn_readfirstlane(ct[n]);
        float a0 = 0.f, a1 = 0.f, a2 = 0.f, a3 = 0.f;
        int i = 0;
        for (; i + 4 <= c; i += 4) {
            float2 p0 = cs[r + i + 0];
            float2 p1 = cs[r + i + 1];
            float2 p2 = cs[r + i + 2];
            float2 p3 = cs[r + i + 3];
            a0 = fmaf(p0.y, hh[(size_t)__float_as_int(p0.x) * 64 + lane], a0);
            a1 = fmaf(p1.y, hh[(size_t)__float_as_int(p1.x) * 64 + lane], a1);
            a2 = fmaf(p2.y, hh[(size_t)__float_as_int(p2.x) * 64 + lane], a2);
            a3 = fmaf(p3.y, hh[(size_t)__float_as_int(p3.x) * 64 + lane], a3);
        }
        for (; i < c; ++i) {
            float2 p = cs[r + i];
            a0 = fmaf(p.y, hh[(size_t)__float_as_int(p.x) * 64 + lane], a0);
        }
        float d = dg[n] + 1.f;
        float v = (a0 + a1) + (a2 + a3) + hh[(size_t)n * 64 + lane] * (1.f / d) + bias;
        psum += fmaxf(v, 0.f);
    }
    red[threadIdx.x] = psum;
    __syncthreads();
    if (wave == 0) {
        float s = red[lane] + red[64 + lane] + red[128 + lane] + red[192 + lane];
        unsafeAtomicAdd(&pooled[br * (NB * 64) + g * 64 + lane], s);
    }
}

// ---------------- final MLP heads
__global__ __launch_bounds__(128) void final_mlp(
    const float* __restrict__ pooled, const float* __restrict__ linker,
    const float* __restrict__ W1, const float* __restrict__ b1,
    const float* __restrict__ W2, const float* __restrict__ b2,
    const float* __restrict__ W3, const float* __restrict__ b3,
    const float* __restrict__ Wcb, const float* __restrict__ bcb,
    const float* __restrict__ Wom, const float* __restrict__ bom,
    const float* __restrict__ Wth, const float* __restrict__ bth,
    const float* __restrict__ Wph, const float* __restrict__ bph,
    float* __restrict__ out) {
    __shared__ float inv[260];
    __shared__ float x1[128];
    __shared__ float x2[64];
    const int g = blockIdx.x;
    const int t = threadIdx.x;
    if (t < 64) {
        float pa = pooled[g * 64 + t];
        float pb = pooled[NB * 64 + g * 64 + t];
        inv[t]       = pa;
        inv[64 + t]  = pa * (1.f / 1024.f);
        inv[128 + t] = pb;
        inv[192 + t] = pb * (1.f / 1024.f);
    }
    if (t == 0) inv[256] = linker[g];
    __syncthreads();

    {
        float a = b1[t];
        for (int i = 0; i < 257; ++i) a = fmaf(inv[i], W1[i * 128 + t], a);
        x1[t] = fmaxf(a, 0.f);
    }
    __syncthreads();
    if (t < 64) {
        float a = b2[t];
        for (int i = 0; i < 128; ++i) a = fmaf(x1[i], W2[i * 64 + t], a);
        x2[t] = fmaxf(a, 0.f);
    }
    __syncthreads();
    if (t < 8) {
        if (t == 0) {
            float a = b3[0];
            for (int i = 0; i < 64; ++i) a = fmaf(x2[i], W3[i], a);
            out[g] = a;
        } else if (t == 1) {
            float a = bcb[0];
            for (int i = 0; i < 64; ++i) a = fmaf(x2[i], Wcb[i], a);
            out[128 + g] = a;
        } else if (t < 4) {
            int j = t - 2; float a = bom[j];
            for (int i = 0; i < 64; ++i) a = fmaf(x2[i], Wom[i * 2 + j], a);
            out[256 + g * 2 + j] = a;
        } else if (t < 6) {
            int j = t - 4; float a = bth[j];
            for (int i = 0; i < 64; ++i) a = fmaf(x2[i], Wth[i * 2 + j], a);
            out[512 + g * 2 + j] = a;
        } else {
            int j = t - 6; float a = bph[j];
            for (int i = 0; i < 64; ++i) a = fmaf(x2[i], Wph[i * 2 + j], a);
            out[768 + g * 2 + j] = a;
        }
    }
}

extern "C" void kernel_launch(void* const* d_in, const int* in_sizes, int n_in,
                              void* d_out, int out_size, void* d_ws, size_t ws_size,
                              hipStream_t stream) {
    const float* x_a  = (const float*)d_in[0];
    const int*   ei_a = (const int*)d_in[1];
    const float* ea_a = (const float*)d_in[2];
    const float* x_b  = (const float*)d_in[4];
    const int*   ei_b = (const int*)d_in[5];
    const float* ea_b = (const float*)d_in[6];
    const float* linker = (const float*)d_in[8];
    const float* W_pre1_a = (const float*)d_in[9];
    const float* b_pre1_a = (const float*)d_in[10];
    const float* W_pre2_a = (const float*)d_in[11];
    const float* b_pre2_a = (const float*)d_in[12];
    const float* W_gcn_a  = (const float*)d_in[13];
    const float* b_gcn_a  = (const float*)d_in[14];
    const float* W_pre1_b = (const float*)d_in[15];
    const float* b_pre1_b = (const float*)d_in[16];
    const float* W_pre2_b = (const float*)d_in[17];
    const float* b_pre2_b = (const float*)d_in[18];
    const float* W_gcn_b  = (const float*)d_in[19];
    const float* b_gcn_b  = (const float*)d_in[20];
    const float* W_lin1 = (const float*)d_in[21];
    const float* b_lin1 = (const float*)d_in[22];
    const float* W_lin2 = (const float*)d_in[23];
    const float* b_lin2 = (const float*)d_in[24];
    const float* W_lin3 = (const float*)d_in[25];
    const float* b_lin3 = (const float*)d_in[26];
    const float* W_cb = (const float*)d_in[27];
    const float* b_cb = (const float*)d_in[28];
    const float* W_om = (const float*)d_in[29];
    const float* b_om = (const float*)d_in[30];
    const float* W_th = (const float*)d_in[31];
    const float* b_th = (const float*)d_in[32];
    const float* W_ph = (const float*)d_in[33];
    const float* b_ph = (const float*)d_in[34];

    float* ws     = (float*)d_ws;
    float* deg    = ws + OFF_DEG;
    float* pooled = ws + OFF_POOLED;
    float* wtw    = ws + OFF_WT;
    float* h      = ws + OFF_H;
    int*   cnt      = (int*)(ws + OFF_CNT);
    int*   rowstart = (int*)(ws + OFF_ROWSTART);
    float2* csr     = (float2*)(ws + OFF_CSR);

    // main path requires the big ws; if absent we'd need the old fallback —
    // ws has always been large enough in this harness (>=105MB), keep simple.
    hipMemsetAsync(pooled, 0, 2 * NB * 64 * sizeof(float), stream);
    wprep<<<6, 256, 0, stream>>>(W_pre1_a, W_pre2_a, W_gcn_a,
                                 W_pre1_b, W_pre2_b, W_gcn_b,
                                 (unsigned short*)wtw);

    hipError_t attr_ok = hipFuncSetAttribute(
        reinterpret_cast<const void*>(&csr_build2),
        hipFuncAttributeMaxDynamicSharedMemorySize, CSRB_LDS);
    if (attr_ok == hipSuccess) {
        csr_build2<<<dim3(NB, 2), 512, CSRB_LDS, stream>>>(ei_a, ea_a, ei_b, ea_b,
                                                           deg, rowstart, cnt, csr);
    } else {
        csr_build<<<dim3(NB, 2), 256, 0, stream>>>(ei_a, ea_a, ei_b, ea_b,
                                                   deg, rowstart, cnt, csr);
    }

    node_mlp_mfma<<<dim3(NNODES / 64, 2), 256, 0, stream>>>(
        x_a, x_b, (const unsigned short*)wtw,
        b_pre1_a, b_pre2_a, b_pre1_b, b_pre2_b, h);
    gcn_gather_pool<<<4096, 256, 0, stream>>>(rowstart, cnt, csr, deg, h,
                                              b_gcn_a, b_gcn_b, pooled);

    final_mlp<<<NB, 128, 0, stream>>>(pooled, linker,
                                      W_lin1, b_lin1, W_lin2, b_lin2, W_lin3, b_lin3,
                                      W_cb, b_cb, W_om, b_om, W_th, b_th, W_ph, b_ph,
                                      (float*)d_out);
}

// Round 8
// 379.195 us; speedup vs baseline: 5.6861x; 1.0703x over previous
//
#include <hip/hip_runtime.h>
#include <hip/hip_bf16.h>

#define NNODES 131072
#define NEDGES 2097152
#define NB     128
#define NPG    1024   // nodes per graph
#define EPG    16384  // edges per graph

// ws layout in 4-byte units. h region is now bf16 (uses half its slot).
#define OFF_DEG      0                                   // 2*NNODES floats
#define OFF_POOLED   (OFF_DEG + 2*NNODES)                // 2*NB*64
#define OFF_WT       (OFF_POOLED + 2*NB*64)              // 96 KB wfrag
#define OFF_H        (OFF_WT + 6*4096)                   // 2*NNODES*64 ushort (slot sized for f32)
#define OFF_CNT      (OFF_H + (size_t)2*NNODES*64)       // 2*NNODES ints
#define OFF_ROWSTART (OFF_CNT + 2*NNODES)                // 2*NNODES ints
#define OFF_CURSOR   (OFF_ROWSTART + 2*NNODES)           // 2*NNODES ints (layout keep)
#define OFF_CSR      (OFF_CURSOR + 2*NNODES)             // 2*NEDGES float2
#define WS_NEEDED    ((OFF_CSR + (size_t)4*NEDGES) * 4)

#define CSRB_LDS 145408   // 128K csr + 4K sdeg + 4K scnt + 4K scur + 2K scan

typedef __attribute__((ext_vector_type(8))) short bfrag;
typedef __attribute__((ext_vector_type(4))) float f32x4;

__device__ __forceinline__ unsigned short f2bf(float v) {
    unsigned int u = __float_as_uint(v);
    unsigned int r = (u + 0x7fffu + ((u >> 16) & 1u)) >> 16;
    return (unsigned short)r;
}
__device__ __forceinline__ float bf2f(unsigned short s) {
    return __uint_as_float(((unsigned int)s) << 16);
}
// non-temporal float2 load (keep the 33.5MB CSR stream out of L2)
__device__ __forceinline__ float2 ntload2(const float2* p) {
    unsigned long long u = __builtin_nontemporal_load(
        reinterpret_cast<const unsigned long long*>(p));
    float2 r;
    r.x = __uint_as_float((unsigned int)(u & 0xffffffffu));
    r.y = __uint_as_float((unsigned int)(u >> 32));
    return r;
}

// ---------------- pack six 64x64 weights into split-bf16 MFMA B-fragments.
// k-convention must equal the A-side assembly (contiguous-8):
//   col f = ft*16 + (lane&15);   k = kt*32 + (lane>>4)*8 + i
__global__ void wprep(const float* __restrict__ w0, const float* __restrict__ w1,
                      const float* __restrict__ w2, const float* __restrict__ w3,
                      const float* __restrict__ w4, const float* __restrict__ w5,
                      unsigned short* __restrict__ wf) {
    int m = blockIdx.x;
    const float* w = (m == 0) ? w0 : (m == 1) ? w1 : (m == 2) ? w2
                   : (m == 3) ? w3 : (m == 4) ? w4 : w5;
    for (int idx = threadIdx.x; idx < 4096; idx += blockDim.x) {
        int ft   = idx >> 10;
        int kt   = (idx >> 9) & 1;
        int lane = (idx >> 3) & 63;
        int i    = idx & 7;
        int f = ft * 16 + (lane & 15);
        int k = kt * 32 + ((lane >> 4) << 3) + i;
        float v = w[k * 64 + f];
        unsigned short hi = f2bf(v);
        unsigned short lo = f2bf(v - bf2f(hi));
        wf[m * 8192 + idx]        = hi;
        wf[m * 8192 + 4096 + idx] = lo;
    }
}

// ---------------- CSR build v2: deg+cnt+scan+fill all in LDS, csr staged in
// LDS and written out COALESCED (float4). block=(g,br), 512 thr, 142 KB LDS.
__global__ __launch_bounds__(512) void csr_build2(
    const int* __restrict__ eia, const float* __restrict__ eaa,
    const int* __restrict__ eib, const float* __restrict__ eab,
    float* __restrict__ deg, int* __restrict__ rowstart,
    int* __restrict__ cnt, float2* __restrict__ csr) {
    extern __shared__ char smem[];
    float2* scsr = (float2*)smem;                    // 128 KB
    float*  sdeg = (float*)(smem + 131072);          // 4 KB
    int*    scnt = (int*)(smem + 135168);            // 4 KB
    int*    scur = (int*)(smem + 139264);            // 4 KB
    int*    sm   = (int*)(smem + 143360);            // 2 KB
    const int g  = blockIdx.x;
    const int br = blockIdx.y;
    const int* ei   = br ? eib : eia;
    const float* ea = br ? eab : eaa;
    const int t     = threadIdx.x;
    const int ebase = g * EPG;
    const int nbase = g * NPG;

    for (int i = t; i < NPG; i += 512) { sdeg[i] = 0.f; scnt[i] = 0; }
    __syncthreads();

#pragma unroll 4
    for (int it = 0; it < EPG / 512; ++it) {
        int e = ebase + it * 512 + t;
        int d = ei[NEDGES + e] - nbase;
        float w = ea[e];
        atomicAdd(&scnt[d], 1);
        atomicAdd(&sdeg[d], w);
    }
    __syncthreads();

    for (int i = t; i < NPG; i += 512) {
        float dv = sdeg[i];
        deg[br * NNODES + nbase + i] = dv;
        sdeg[i] = rsqrtf(dv + 1.f);
    }

    int c0 = scnt[t * 2 + 0], c1 = scnt[t * 2 + 1];
    int T = c0 + c1;
    sm[t] = T;
    __syncthreads();
    for (int off = 1; off < 512; off <<= 1) {
        int v = (t >= off) ? sm[t - off] : 0;
        __syncthreads();
        sm[t] += v;
        __syncthreads();
    }
    int excl = sm[t] - T;
    int r0 = excl, r1 = excl + c0;
    int nout = br * NNODES + nbase + t * 2;
    rowstart[nout + 0] = ebase + r0;
    rowstart[nout + 1] = ebase + r1;
    cnt[nout + 0] = c0; cnt[nout + 1] = c1;
    scur[t * 2 + 0] = r0; scur[t * 2 + 1] = r1;
    __syncthreads();

#pragma unroll 4
    for (int it = 0; it < EPG / 512; ++it) {
        int e = ebase + it * 512 + t;
        int srcg = ei[e];
        int s = srcg - nbase;
        int d = ei[NEDGES + e] - nbase;
        float w = ea[e];
        int pos = atomicAdd(&scur[d], 1);
        float2 pr;
        pr.x = __int_as_float(srcg);
        pr.y = sdeg[s] * w * sdeg[d];
        scsr[pos] = pr;
    }
    __syncthreads();

    float4* dst4 = (float4*)(csr + (size_t)br * NEDGES + ebase);
    const float4* src4 = (const float4*)scsr;
    for (int i = t; i < 8192; i += 512) dst4[i] = src4[i];
}

// ---------------- fallback CSR build (static 13 KB LDS)
__global__ __launch_bounds__(256) void csr_build(
    const int* __restrict__ eia, const float* __restrict__ eaa,
    const int* __restrict__ eib, const float* __restrict__ eab,
    float* __restrict__ deg, int* __restrict__ rowstart,
    int* __restrict__ cnt, float2* __restrict__ csr) {
    __shared__ float sdeg[NPG];
    __shared__ int   scnt[NPG];
    __shared__ int   scur[NPG];
    __shared__ int   sm[256];
    const int g  = blockIdx.x;
    const int br = blockIdx.y;
    const int* ei   = br ? eib : eia;
    const float* ea = br ? eab : eaa;
    const int t     = threadIdx.x;
    const int ebase = g * EPG;
    const int nbase = g * NPG;

    for (int i = t; i < NPG; i += 256) { sdeg[i] = 0.f; scnt[i] = 0; }
    __syncthreads();
#pragma unroll 4
    for (int it = 0; it < EPG / 256; ++it) {
        int e = ebase + it * 256 + t;
        int d = ei[NEDGES + e] - nbase;
        float w = ea[e];
        atomicAdd(&scnt[d], 1);
        atomicAdd(&sdeg[d], w);
    }
    __syncthreads();
    for (int i = t; i < NPG; i += 256) {
        float dv = sdeg[i];
        deg[br * NNODES + nbase + i] = dv;
        sdeg[i] = rsqrtf(dv + 1.f);
    }
    int c0 = scnt[t * 4 + 0], c1 = scnt[t * 4 + 1], c2 = scnt[t * 4 + 2], c3 = scnt[t * 4 + 3];
    int T = c0 + c1 + c2 + c3;
    sm[t] = T;
    __syncthreads();
    for (int off = 1; off < 256; off <<= 1) {
        int v = (t >= off) ? sm[t - off] : 0;
        __syncthreads();
        sm[t] += v;
        __syncthreads();
    }
    int excl = sm[t] - T;
    int base = ebase + excl;
    int r0 = base, r1 = base + c0, r2 = r1 + c1, r3 = r2 + c2;
    int nout = br * NNODES + nbase + t * 4;
    rowstart[nout + 0] = r0; rowstart[nout + 1] = r1;
    rowstart[nout + 2] = r2; rowstart[nout + 3] = r3;
    cnt[nout + 0] = c0; cnt[nout + 1] = c1; cnt[nout + 2] = c2; cnt[nout + 3] = c3;
    scur[t * 4 + 0] = r0; scur[t * 4 + 1] = r1;
    scur[t * 4 + 2] = r2; scur[t * 4 + 3] = r3;
    __syncthreads();
    float2* cso = csr + (size_t)br * NEDGES;
#pragma unroll 4
    for (int it = 0; it < EPG / 256; ++it) {
        int e = ebase + it * 256 + t;
        int srcg = ei[e];
        int s = srcg - nbase;
        int d = ei[NEDGES + e] - nbase;
        float w = ea[e];
        int pos = atomicAdd(&scur[d], 1);
        float2 pr;
        pr.x = __int_as_float(srcg);
        pr.y = sdeg[s] * w * sdeg[d];
        cso[pos] = pr;
    }
}

// ---------------- MFMA node MLP: h = relu(relu(x@W1+b1)@W2+b2)@Wg
// Split-bf16 internally (error ~2^-18 rel); OUTPUT h stored as bf16 (one
// extra RNE rounding — halves gather read + mlp write traffic).
__global__ __launch_bounds__(256) void node_mlp_mfma(
    const float* __restrict__ xa, const float* __restrict__ xb,
    const unsigned short* __restrict__ wf,
    const float* __restrict__ b1a, const float* __restrict__ b2a,
    const float* __restrict__ b1b, const float* __restrict__ b2b,
    unsigned short* __restrict__ hout) {
    __shared__ float lds[4 * 16 * 65];
    const int br = blockIdx.y;
    const float* x = br ? xb : xa;
    const unsigned short* wfb = wf + br * 3 * 8192;
    const float* b1 = br ? b1b : b1a;
    const float* b2 = br ? b2b : b2a;
    const int wave = threadIdx.x >> 6;
    const int lane = threadIdx.x & 63;
    const int row  = lane & 15;
    const int kg   = lane >> 4;
    const int n0   = blockIdx.x * 64 + wave * 16;
    float* wlds = &lds[wave * 16 * 65];

    bfrag ahi[2], alo[2];
#pragma unroll
    for (int kt = 0; kt < 2; ++kt) {
        const float4* p = reinterpret_cast<const float4*>(
            x + (size_t)(n0 + row) * 64 + kt * 32 + kg * 8);
        float4 v0 = p[0], v1 = p[1];
        float vv[8] = {v0.x, v0.y, v0.z, v0.w, v1.x, v1.y, v1.z, v1.w};
        bfrag h, l;
#pragma unroll
        for (int i = 0; i < 8; ++i) {
            unsigned short hb = f2bf(vv[i]);
            unsigned short lb = f2bf(vv[i] - bf2f(hb));
            h[i] = (short)hb;
            l[i] = (short)lb;
        }
        ahi[kt] = h; alo[kt] = l;
    }

#pragma unroll
    for (int layer = 0; layer < 3; ++layer) {
        const unsigned short* wl = wfb + layer * 8192;
        bfrag bhi[4][2], blo[4][2];
#pragma unroll
        for (int ft = 0; ft < 4; ++ft)
#pragma unroll
            for (int kt = 0; kt < 2; ++kt) {
                bhi[ft][kt] = *reinterpret_cast<const bfrag*>(wl + ft * 1024 + kt * 512 + lane * 8);
                blo[ft][kt] = *reinterpret_cast<const bfrag*>(wl + 4096 + ft * 1024 + kt * 512 + lane * 8);
            }
        f32x4 acc[4];
#pragma unroll
        for (int ft = 0; ft < 4; ++ft) {
            float bv = (layer == 0) ? b1[ft * 16 + row]
                     : (layer == 1) ? b2[ft * 16 + row] : 0.f;
            acc[ft] = (f32x4){bv, bv, bv, bv};
        }
#pragma unroll
        for (int ft = 0; ft < 4; ++ft)
#pragma unroll
            for (int kt = 0; kt < 2; ++kt) {
                acc[ft] = __builtin_amdgcn_mfma_f32_16x16x32_bf16(ahi[kt], bhi[ft][kt], acc[ft], 0, 0, 0);
                acc[ft] = __builtin_amdgcn_mfma_f32_16x16x32_bf16(alo[kt], bhi[ft][kt], acc[ft], 0, 0, 0);
                acc[ft] = __builtin_amdgcn_mfma_f32_16x16x32_bf16(ahi[kt], blo[ft][kt], acc[ft], 0, 0, 0);
            }

        if (layer < 2) {
#pragma unroll
            for (int ft = 0; ft < 4; ++ft)
#pragma unroll
                for (int r = 0; r < 4; ++r)
                    wlds[(kg * 4 + r) * 65 + ft * 16 + row] = fmaxf(acc[ft][r], 0.f);
            __syncthreads();
#pragma unroll
            for (int kt = 0; kt < 2; ++kt) {
                const float* rp = &wlds[row * 65 + kt * 32 + kg * 8];
                bfrag h, l;
#pragma unroll
                for (int i = 0; i < 8; ++i) {
                    float v = rp[i];
                    unsigned short hb = f2bf(v);
                    unsigned short lb = f2bf(v - bf2f(hb));
                    h[i] = (short)hb;
                    l[i] = (short)lb;
                }
                ahi[kt] = h; alo[kt] = l;
            }
            __syncthreads();
        } else {
            unsigned short* hp = hout + (size_t)br * NNODES * 64 + (size_t)n0 * 64;
#pragma unroll
            for (int ft = 0; ft < 4; ++ft)
#pragma unroll
                for (int r = 0; r < 4; ++r)
                    hp[(kg * 4 + r) * 64 + ft * 16 + row] = f2bf(acc[ft][r]);
        }
    }
}

// ---------------- CSR gather GCN (bf16 h) + self loop + bias + relu + pool
// 8-wide edge ILP; nt loads on the CSR stream.
__global__ __launch_bounds__(256) void gcn_gather_pool(
    const int* __restrict__ rowstart, const int* __restrict__ cnt,
    const float2* __restrict__ csr, const float* __restrict__ deg,
    const unsigned short* __restrict__ h,
    const float* __restrict__ bga, const float* __restrict__ bgb,
    float* __restrict__ pooled) {
    __shared__ float red[256];
    const int bid  = blockIdx.x;
    const int xcd  = bid & 7;
    const int sub  = bid >> 3;                  // 0..511
    const int gb   = xcd * 32 + (sub >> 4);     // graph-branch pair 0..255
    const int blk  = sub & 15;
    const int br   = gb >> 7;
    const int g    = gb & 127;
    const int wave = threadIdx.x >> 6;
    const int lane = threadIdx.x & 63;
    const int n0   = g * NPG + blk * 64 + wave * 16;

    const int*    rs = rowstart + br * NNODES;
    const int*    ct = cnt + br * NNODES;
    const float2* cs = csr + (size_t)br * NEDGES;
    const float*  dg = deg + br * NNODES;
    const unsigned short* hh = h + (size_t)br * NNODES * 64;
    const float bias = (br ? bgb : bga)[lane];

    float psum = 0.f;
    for (int j = 0; j < 16; ++j) {
        int n = n0 + j;
        int r = __builtin_amdgcn_readfirstlane(rs[n]);
        int c = __builtin_amdgcn_readfirstlane(ct[n]);
        float s0 = 0.f, s1 = 0.f, s2 = 0.f, s3 = 0.f;
        float s4 = 0.f, s5 = 0.f, s6 = 0.f, s7 = 0.f;
        int i = 0;
        for (; i + 8 <= c; i += 8) {
            float2 p0 = ntload2(cs + r + i + 0);
            float2 p1 = ntload2(cs + r + i + 1);
            float2 p2 = ntload2(cs + r + i + 2);
            float2 p3 = ntload2(cs + r + i + 3);
            float2 p4 = ntload2(cs + r + i + 4);
            float2 p5 = ntload2(cs + r + i + 5);
            float2 p6 = ntload2(cs + r + i + 6);
            float2 p7 = ntload2(cs + r + i + 7);
            s0 = fmaf(p0.y, bf2f(hh[(size_t)__float_as_int(p0.x) * 64 + lane]), s0);
            s1 = fmaf(p1.y, bf2f(hh[(size_t)__float_as_int(p1.x) * 64 + lane]), s1);
            s2 = fmaf(p2.y, bf2f(hh[(size_t)__float_as_int(p2.x) * 64 + lane]), s2);
            s3 = fmaf(p3.y, bf2f(hh[(size_t)__float_as_int(p3.x) * 64 + lane]), s3);
            s4 = fmaf(p4.y, bf2f(hh[(size_t)__float_as_int(p4.x) * 64 + lane]), s4);
            s5 = fmaf(p5.y, bf2f(hh[(size_t)__float_as_int(p5.x) * 64 + lane]), s5);
            s6 = fmaf(p6.y, bf2f(hh[(size_t)__float_as_int(p6.x) * 64 + lane]), s6);
            s7 = fmaf(p7.y, bf2f(hh[(size_t)__float_as_int(p7.x) * 64 + lane]), s7);
        }
        for (; i + 4 <= c; i += 4) {
            float2 p0 = ntload2(cs + r + i + 0);
            float2 p1 = ntload2(cs + r + i + 1);
            float2 p2 = ntload2(cs + r + i + 2);
            float2 p3 = ntload2(cs + r + i + 3);
            s0 = fmaf(p0.y, bf2f(hh[(size_t)__float_as_int(p0.x) * 64 + lane]), s0);
            s1 = fmaf(p1.y, bf2f(hh[(size_t)__float_as_int(p1.x) * 64 + lane]), s1);
            s2 = fmaf(p2.y, bf2f(hh[(size_t)__float_as_int(p2.x) * 64 + lane]), s2);
            s3 = fmaf(p3.y, bf2f(hh[(size_t)__float_as_int(p3.x) * 64 + lane]), s3);
        }
        for (; i < c; ++i) {
            float2 p = ntload2(cs + r + i);
            s0 = fmaf(p.y, bf2f(hh[(size_t)__float_as_int(p.x) * 64 + lane]), s0);
        }
        float d = dg[n] + 1.f;
        float v = ((s0 + s1) + (s2 + s3)) + ((s4 + s5) + (s6 + s7))
                + bf2f(hh[(size_t)n * 64 + lane]) * (1.f / d) + bias;
        psum += fmaxf(v, 0.f);
    }
    red[threadIdx.x] = psum;
    __syncthreads();
    if (wave == 0) {
        float s = red[lane] + red[64 + lane] + red[128 + lane] + red[192 + lane];
        unsafeAtomicAdd(&pooled[br * (NB * 64) + g * 64 + lane], s);
    }
}

// ---------------- final MLP heads
__global__ __launch_bounds__(128) void final_mlp(
    const float* __restrict__ pooled, const float* __restrict__ linker,
    const float* __restrict__ W1, const float* __restrict__ b1,
    const float* __restrict__ W2, const float* __restrict__ b2,
    const float* __restrict__ W3, const float* __restrict__ b3,
    const float* __restrict__ Wcb, const float* __restrict__ bcb,
    const float* __restrict__ Wom, const float* __restrict__ bom,
    const float* __restrict__ Wth, const float* __restrict__ bth,
    const float* __restrict__ Wph, const float* __restrict__ bph,
    float* __restrict__ out) {
    __shared__ float inv[260];
    __shared__ float x1[128];
    __shared__ float x2[64];
    const int g = blockIdx.x;
    const int t = threadIdx.x;
    if (t < 64) {
        float pa = pooled[g * 64 + t];
        float pb = pooled[NB * 64 + g * 64 + t];
        inv[t]       = pa;
        inv[64 + t]  = pa * (1.f / 1024.f);
        inv[128 + t] = pb;
        inv[192 + t] = pb * (1.f / 1024.f);
    }
    if (t == 0) inv[256] = linker[g];
    __syncthreads();

    {
        float a = b1[t];
        for (int i = 0; i < 257; ++i) a = fmaf(inv[i], W1[i * 128 + t], a);
        x1[t] = fmaxf(a, 0.f);
    }
    __syncthreads();
    if (t < 64) {
        float a = b2[t];
        for (int i = 0; i < 128; ++i) a = fmaf(x1[i], W2[i * 64 + t], a);
        x2[t] = fmaxf(a, 0.f);
    }
    __syncthreads();
    if (t < 8) {
        if (t == 0) {
            float a = b3[0];
            for (int i = 0; i < 64; ++i) a = fmaf(x2[i], W3[i], a);
            out[g] = a;
        } else if (t == 1) {
            float a = bcb[0];
            for (int i = 0; i < 64; ++i) a = fmaf(x2[i], Wcb[i], a);
            out[128 + g] = a;
        } else if (t < 4) {
            int j = t - 2; float a = bom[j];
            for (int i = 0; i < 64; ++i) a = fmaf(x2[i], Wom[i * 2 + j], a);
            out[256 + g * 2 + j] = a;
        } else if (t < 6) {
            int j = t - 4; float a = bth[j];
            for (int i = 0; i < 64; ++i) a = fmaf(x2[i], Wth[i * 2 + j], a);
            out[512 + g * 2 + j] = a;
        } else {
            int j = t - 6; float a = bph[j];
            for (int i = 0; i < 64; ++i) a = fmaf(x2[i], Wph[i * 2 + j], a);
            out[768 + g * 2 + j] = a;
        }
    }
}

extern "C" void kernel_launch(void* const* d_in, const int* in_sizes, int n_in,
                              void* d_out, int out_size, void* d_ws, size_t ws_size,
                              hipStream_t stream) {
    const float* x_a  = (const float*)d_in[0];
    const int*   ei_a = (const int*)d_in[1];
    const float* ea_a = (const float*)d_in[2];
    const float* x_b  = (const float*)d_in[4];
    const int*   ei_b = (const int*)d_in[5];
    const float* ea_b = (const float*)d_in[6];
    const float* linker = (const float*)d_in[8];
    const float* W_pre1_a = (const float*)d_in[9];
    const float* b_pre1_a = (const float*)d_in[10];
    const float* W_pre2_a = (const float*)d_in[11];
    const float* b_pre2_a = (const float*)d_in[12];
    const float* W_gcn_a  = (const float*)d_in[13];
    const float* b_gcn_a  = (const float*)d_in[14];
    const float* W_pre1_b = (const float*)d_in[15];
    const float* b_pre1_b = (const float*)d_in[16];
    const float* W_pre2_b = (const float*)d_in[17];
    const float* b_pre2_b = (const float*)d_in[18];
    const float* W_gcn_b  = (const float*)d_in[19];
    const float* b_gcn_b  = (const float*)d_in[20];
    const float* W_lin1 = (const float*)d_in[21];
    const float* b_lin1 = (const float*)d_in[22];
    const float* W_lin2 = (const float*)d_in[23];
    const float* b_lin2 = (const float*)d_in[24];
    const float* W_lin3 = (const float*)d_in[25];
    const float* b_lin3 = (const float*)d_in[26];
    const float* W_cb = (const float*)d_in[27];
    const float* b_cb = (const float*)d_in[28];
    const float* W_om = (const float*)d_in[29];
    const float* b_om = (const float*)d_in[30];
    const float* W_th = (const float*)d_in[31];
    const float* b_th = (const float*)d_in[32];
    const float* W_ph = (const float*)d_in[33];
    const float* b_ph = (const float*)d_in[34];

    float* ws     = (float*)d_ws;
    float* deg    = ws + OFF_DEG;
    float* pooled = ws + OFF_POOLED;
    float* wtw    = ws + OFF_WT;
    unsigned short* h = (unsigned short*)(ws + OFF_H);
    int*   cnt      = (int*)(ws + OFF_CNT);
    int*   rowstart = (int*)(ws + OFF_ROWSTART);
    float2* csr     = (float2*)(ws + OFF_CSR);

    hipMemsetAsync(pooled, 0, 2 * NB * 64 * sizeof(float), stream);
    wprep<<<6, 256, 0, stream>>>(W_pre1_a, W_pre2_a, W_gcn_a,
                                 W_pre1_b, W_pre2_b, W_gcn_b,
                                 (unsigned short*)wtw);

    hipError_t attr_ok = hipFuncSetAttribute(
        reinterpret_cast<const void*>(&csr_build2),
        hipFuncAttributeMaxDynamicSharedMemorySize, CSRB_LDS);
    if (attr_ok == hipSuccess) {
        csr_build2<<<dim3(NB, 2), 512, CSRB_LDS, stream>>>(ei_a, ea_a, ei_b, ea_b,
                                                           deg, rowstart, cnt, csr);
    } else {
        csr_build<<<dim3(NB, 2), 256, 0, stream>>>(ei_a, ea_a, ei_b, ea_b,
                                                   deg, rowstart, cnt, csr);
    }

    node_mlp_mfma<<<dim3(NNODES / 64, 2), 256, 0, stream>>>(
        x_a, x_b, (const unsigned short*)wtw,
        b_pre1_a, b_pre2_a, b_pre1_b, b_pre2_b, h);
    gcn_gather_pool<<<4096, 256, 0, stream>>>(rowstart, cnt, csr, deg, h,
                                              b_gcn_a, b_gcn_b, pooled);

    final_mlp<<<NB, 128, 0, stream>>>(pooled, linker,
                                      W_lin1, b_lin1, W_lin2, b_lin2, W_lin3, b_lin3,
                                      W_cb, b_cb, W_om, b_om, W_th, b_th, W_ph, b_ph,
                                      (float*)d_out);
}